// Round 1
// 453.033 us; speedup vs baseline: 1.0220x; 1.0220x over previous
//
#include <hip/hip_runtime.h>

#define N_NODES 50000
#define N_EDGES 400000
#define EMB 32
#define NREL 8
#define NLAYER 5
#define NPB 16          // nodes per block (8 waves x 2 sequential passes)
#define KROWS 43        // 0..31 P, 32 Stot, 33..40 S_r, 41 h_dst(rgcnRoot), 42 h_dst(nnRoot)
#define NCHUNK 196      // ceil(50000/256) scan chunks

typedef __attribute__((ext_vector_type(8))) short short8;   // 8 bf16 (4 VGPRs)
typedef __attribute__((ext_vector_type(4))) float f32x4;    // MFMA accumulator
typedef __attribute__((ext_vector_type(4))) unsigned int u32x4v;

__device__ __forceinline__ unsigned short f2bf(float f) {   // RNE f32 -> bf16
    unsigned u = __float_as_uint(f);
    unsigned r = u + 0x7FFF + ((u >> 16) & 1);
    return (unsigned short)(r >> 16);
}

// packed RNE f32x2 -> bf16x2 (lo = a, hi = b)
__device__ __forceinline__ unsigned cvt_pk(float a, float b) {
    unsigned r;
    asm("v_cvt_pk_bf16_f32 %0, %1, %2" : "=v"(r) : "v"(a), "v"(b));
    return r;
}

// ---------------- setup kernels ----------------

__global__ __launch_bounds__(256) void zero_kernel(int* __restrict__ p, int n) {
    int i = blockIdx.x * 256 + threadIdx.x;
    if (i < n) p[i] = 0;
}

__global__ __launch_bounds__(256) void hist_kernel(const int* __restrict__ ei,
                                                   const int* __restrict__ et,
                                                   int* __restrict__ deg,
                                                   int* __restrict__ relcnt) {
    int e = blockIdx.x * 256 + threadIdx.x;
    if (e < N_EDGES) {
        int d = ei[N_EDGES + e];           // dst = edge_index[1]
        atomicAdd(&deg[d], 1);
        atomicAdd(&relcnt[d * NREL + et[e]], 1);
    }
}

// per-chunk sum of deg
__global__ __launch_bounds__(256) void bsum_kernel(const int* __restrict__ deg,
                                                   int* __restrict__ bsum) {
    __shared__ int wsum[4];
    int tid = threadIdx.x, lane = tid & 63, w = tid >> 6;
    int i = blockIdx.x * 256 + tid;
    int v = (i < N_NODES) ? deg[i] : 0;
    #pragma unroll
    for (int off = 32; off > 0; off >>= 1) v += __shfl_down(v, off, 64);
    if (lane == 0) wsum[w] = v;
    __syncthreads();
    if (tid == 0) bsum[blockIdx.x] = wsum[0] + wsum[1] + wsum[2] + wsum[3];
}

// scan chunk sums -> boff; row_ptr[N]=E
__global__ __launch_bounds__(256) void boff_kernel(const int* __restrict__ bsum,
                                                   int* __restrict__ boff,
                                                   int* __restrict__ row_ptr) {
    __shared__ int ws[4];
    int tid = threadIdx.x, lane = tid & 63, w = tid >> 6;
    int v = (tid < NCHUNK) ? bsum[tid] : 0;
    int incl = v;
    #pragma unroll
    for (int off = 1; off < 64; off <<= 1) {
        int t = __shfl_up(incl, off, 64);
        if (lane >= off) incl += t;
    }
    if (lane == 63) ws[w] = incl;
    __syncthreads();
    int add = 0;
    for (int j = 0; j < w; j++) add += ws[j];
    if (tid < NCHUNK) boff[tid] = add + incl - v;
    if (tid == 0) row_ptr[N_NODES] = N_EDGES;
}

// per-chunk exclusive scan + chunk offset -> row_ptr
__global__ __launch_bounds__(256) void rptr_kernel(const int* __restrict__ deg,
                                                   const int* __restrict__ boff,
                                                   int* __restrict__ row_ptr) {
    __shared__ int ws[4];
    int tid = threadIdx.x, lane = tid & 63, w = tid >> 6;
    int i = blockIdx.x * 256 + tid;
    int v = (i < N_NODES) ? deg[i] : 0;
    int incl = v;
    #pragma unroll
    for (int off = 1; off < 64; off <<= 1) {
        int t = __shfl_up(incl, off, 64);
        if (lane >= off) incl += t;
    }
    if (lane == 63) ws[w] = incl;
    __syncthreads();
    int add = boff[blockIdx.x];
    for (int j = 0; j < w; j++) add += ws[j];
    if (i < N_NODES) row_ptr[i] = add + incl - v;
}

__global__ __launch_bounds__(256) void inv_kernel(const int* __restrict__ deg,
                                                  const int* __restrict__ relcnt,
                                                  float* __restrict__ invdeg,
                                                  float* __restrict__ invcnt) {
    int n = blockIdx.x * 256 + threadIdx.x;
    if (n < N_NODES) {
        int d = deg[n];
        invdeg[n] = 1.0f / (float)(d > 0 ? d : 1);
        #pragma unroll
        for (int r = 0; r < NREL; r++) {
            int c = relcnt[n * NREL + r];
            invcnt[n * NREL + r] = 1.0f / (float)(c > 0 ? c : 1);
        }
    }
}

__global__ __launch_bounds__(256) void scatter_kernel(const int* __restrict__ ei,
                                                      const int* __restrict__ et,
                                                      const float* __restrict__ ed,
                                                      const int* __restrict__ row_ptr,
                                                      int* __restrict__ cursor,
                                                      int2* __restrict__ edge2) {
    int e = blockIdx.x * 256 + threadIdx.x;
    if (e < N_EDGES) {
        int d = ei[N_EDGES + e];
        int pos = row_ptr[d] + atomicAdd(&cursor[d], 1);
        edge2[pos] = make_int2(ei[e] | (et[e] << 16), __float_as_int(ed[e]));
    }
}

// transpose+bf16 contraction weights with interleaved-k permutation:
//   k-slot k holds input index i(k) = (k>>1) + ((k&1)<<4)
//   WB[m][o*32+k] = bf16(src_m[i(k)*32 + o])
// m 0..31: W2 rows; 32: b2; 33+l*10+j: j<8 rgcnW[l][j], j==8 rgcnRoot[l], j==9 nnRoot[l]
__global__ __launch_bounds__(256) void wtbf_kernel(const float* __restrict__ W2,
                                                   const float* __restrict__ b2,
                                                   const float* __restrict__ rgcnW,
                                                   const float* __restrict__ rgcnRoot,
                                                   const float* __restrict__ nnRoot,
                                                   unsigned short* __restrict__ WB) {
    int m = blockIdx.x;
    const float* src;
    if (m < 32) src = W2 + (size_t)m * 1024;
    else if (m == 32) src = b2;
    else {
        int t = m - 33, l = t / 10, j = t % 10;
        src = (j < 8) ? rgcnW + (size_t)(l * 8 + j) * 1024
            : (j == 8) ? rgcnRoot + (size_t)l * 1024
                       : nnRoot + (size_t)l * 1024;
    }
    unsigned short* dst = WB + (size_t)m * 1024;
    #pragma unroll
    for (int c = 0; c < 4; c++) {
        int idx = c * 256 + threadIdx.x;
        int o = idx >> 5, k = idx & 31;
        int i = (k >> 1) + ((k & 1) << 4);
        dst[o * 32 + k] = f2bf(src[i * 32 + o]);
    }
}

// ---------------- fc: h0 = relu(x @ fc_W + fc_b) ----------------

__global__ __launch_bounds__(256) void fc_kernel(const float* __restrict__ x,
                                                 const float* __restrict__ W,
                                                 const float* __restrict__ b,
                                                 float* __restrict__ h) {
    __shared__ __align__(16) float xt[8][EMB];
    int tid = threadIdx.x;
    int nl = tid >> 5, lane = tid & 31;
    int n0 = blockIdx.x * 8;
    xt[tid >> 5][tid & 31] = x[n0 * EMB + tid];
    __syncthreads();
    float acc = b[lane];
    #pragma unroll
    for (int i = 0; i < EMB; i++) acc += xt[nl][i] * W[i * EMB + lane];
    h[(n0 + nl) * EMB + lane] = fmaxf(acc, 0.0f);
}

// ---------------- fused layer kernel (MFMA edge phase + MFMA contraction) ----------------
// Edge phase: one wave per node, 2 sequential node passes per wave (16 nodes/block).
// Per node: G[41,32] = Coef[41,E_n] x Hsrc[E_n,32] as K=32-edge MFMA chunks:
//   A tiles = hid rows (0-15 / 16-31), S-tile A = [Stot; onehot(r)x8; 0...] (16 rows)
//   B tiles = h[src] gathers (cols 0-15 / 16-31), shared across all 6 MFMAs.
// A-fragment: row = lane&15, k = (lane>>4)*8 + j  (derived from the proven contraction).
// D: row = (lane>>4)*4 + reg, col = lane&15.
// Staged A columns use interleaved order col' = 2m (i=m) / 2m+1 (i=m+16) so each
// LDS store is one packed cvt_pk b32 write; WB k-order is permuted to match.
__global__ __launch_bounds__(512, 6) void layer_kernel(
    const float* __restrict__ h,
    const int2* __restrict__ edge2,
    const int* __restrict__ row_ptr,
    const float* __restrict__ invdeg,
    const float* __restrict__ invcnt,
    const float* __restrict__ W1,
    const float* __restrict__ b1,
    const unsigned short* __restrict__ WBs,   // rows 0..32 (W2^T, b2^T)
    const unsigned short* __restrict__ WBl,   // rows 33..42 (rgcnW^T x8, rgcnRoot^T, nnRoot^T)
    const float* __restrict__ rgcnBias_l,
    const float* __restrict__ nnBias_l,
    float* __restrict__ hout)
{
    __shared__ __align__(16) unsigned short P_lds[NPB][KROWS][EMB];  // 44032 B
    __shared__ __align__(16) float wrb2[NREL][32];                   // [r][2m+half] = W1[1+r][m+16*half]+b1
    // total 45056 B -> 3 blocks/CU

    const int tid = threadIdx.x;
    const int n0 = blockIdx.x * NPB;

    // stage per-relation hid constants: wrb2[r][2m]   = W1[1+r][m]    + b1[m]
    //                                   wrb2[r][2m+1] = W1[1+r][m+16] + b1[m+16]
    if (tid < 256) {
        int r = tid >> 5, i = tid & 31;
        int mm = (i >> 1) + ((i & 1) << 4);
        wrb2[r][i] = W1[(1 + r) * EMB + mm] + b1[mm];
    }
    __syncthreads();

    const int l    = tid & 63;
    const int w    = tid >> 6;        // wave 0..7
    const int quad = l >> 4;          // 0..3
    const int m    = l & 15;
    const float w10_0 = W1[m];        // W1[0][m]
    const float w10_1 = W1[m + 16];   // W1[0][m+16]

    for (int pass = 0; pass < 2; ++pass) {
        const int hw = w + pass * 8;          // node slot 0..15
        const int n  = n0 + hw;
        const int pb = row_ptr[n], pe = row_ptr[n + 1];

        f32x4 aP00 = {0.f, 0.f, 0.f, 0.f}, aP01 = {0.f, 0.f, 0.f, 0.f};
        f32x4 aP10 = {0.f, 0.f, 0.f, 0.f}, aP11 = {0.f, 0.f, 0.f, 0.f};
        f32x4 aS0  = {0.f, 0.f, 0.f, 0.f}, aS1  = {0.f, 0.f, 0.f, 0.f};

        for (int c0 = pb; c0 < pe; c0 += 32) {
            const int ebase = c0 + quad * 8;  // this lane-group's first edge (k-slot base)
            const int slack = pe - ebase;     // j valid iff j < slack
            const int2* ep = edge2 + ebase;
            u32x4v fa0, fa1, fas, fb0, fb1;
            #pragma unroll
            for (int jp = 0; jp < 4; ++jp) {
                int2 ea = ep[2 * jp];         // reads past segment end are mapped ws memory;
                int2 eb = ep[2 * jp + 1];     // contributions masked below
                const bool va = (2 * jp)     < slack;
                const bool vb = (2 * jp + 1) < slack;
                int ra = (ea.x >> 16) & 7, rb = (eb.x >> 16) & 7;
                const float2 wa = *(const float2*)&wrb2[ra][2 * m];
                const float2 wb = *(const float2*)&wrb2[rb][2 * m];
                float da = __int_as_float(ea.y), db = __int_as_float(eb.y);
                float hA0 = va ? fmaxf(fmaf(da, w10_0, wa.x), 0.f) : 0.f;
                float hA1 = va ? fmaxf(fmaf(da, w10_1, wa.y), 0.f) : 0.f;
                float hB0 = vb ? fmaxf(fmaf(db, w10_0, wb.x), 0.f) : 0.f;
                float hB1 = vb ? fmaxf(fmaf(db, w10_1, wb.y), 0.f) : 0.f;
                fa0[jp] = cvt_pk(hA0, hB0);           // A rows m / edges 2jp,2jp+1
                fa1[jp] = cvt_pk(hA1, hB1);           // A rows m+16
                float sA = (va && (m == 0 || ra == m - 1)) ? 1.f : 0.f;
                float sB = (vb && (m == 0 || rb == m - 1)) ? 1.f : 0.f;
                fas[jp] = cvt_pk(sA, sB);             // S-tile coeffs (row0=Stot, row 1+r=onehot)
                int offa = va ? ((ea.x & 0xFFFF) << 5) + m : m;   // clamp invalid -> h[m] (finite)
                int offb = vb ? ((eb.x & 0xFFFF) << 5) + m : m;
                float bA0 = h[offa], bA1 = h[offa + 16];
                float bB0 = h[offb], bB1 = h[offb + 16];
                fb0[jp] = cvt_pk(bA0, bB0);           // B cols m
                fb1[jp] = cvt_pk(bA1, bB1);           // B cols m+16
            }
            short8 A0 = __builtin_bit_cast(short8, fa0);
            short8 A1 = __builtin_bit_cast(short8, fa1);
            short8 AS = __builtin_bit_cast(short8, fas);
            short8 B0 = __builtin_bit_cast(short8, fb0);
            short8 B1 = __builtin_bit_cast(short8, fb1);
            aP00 = __builtin_amdgcn_mfma_f32_16x16x32_bf16(A0, B0, aP00, 0, 0, 0);
            aP01 = __builtin_amdgcn_mfma_f32_16x16x32_bf16(A0, B1, aP01, 0, 0, 0);
            aP10 = __builtin_amdgcn_mfma_f32_16x16x32_bf16(A1, B0, aP10, 0, 0, 0);
            aP11 = __builtin_amdgcn_mfma_f32_16x16x32_bf16(A1, B1, aP11, 0, 0, 0);
            aS0  = __builtin_amdgcn_mfma_f32_16x16x32_bf16(AS, B0, aS0, 0, 0, 0);
            aS1  = __builtin_amdgcn_mfma_f32_16x16x32_bf16(AS, B1, aS1, 0, 0, 0);
        }

        // ---------- stage bf16 A-rows, pre-scaled (packed b32 writes) ----------
        const float idg = invdeg[n];
        #pragma unroll
        for (int reg = 0; reg < 4; ++reg) {
            const int row = quad * 4 + reg;   // D row within tile
            *(unsigned*)&P_lds[hw][row][2 * m] =
                cvt_pk(aP00[reg] * idg, aP01[reg] * idg);
            *(unsigned*)&P_lds[hw][row + 16][2 * m] =
                cvt_pk(aP10[reg] * idg, aP11[reg] * idg);
            if (row <= 8) {                   // S rows: 0 -> Stot(32), 1..8 -> S_r(33..40)
                const float sc = (row == 0) ? idg : invcnt[n * NREL + row - 1];
                *(unsigned*)&P_lds[hw][32 + row][2 * m] =
                    cvt_pk(aS0[reg] * sc, aS1[reg] * sc);
            }
        }
        if (quad < 2) {                       // rows 41 (rgcnRoot) / 42 (nnRoot): h_dst
            float h0 = h[n * EMB + m], h1 = h[n * EMB + m + 16];
            *(unsigned*)&P_lds[hw][41 + quad][2 * m] = cvt_pk(h0, h1);
        }
    }
    __syncthreads();

    // ---------- MFMA contraction (unchanged; WB k-order matches staged columns) ----------
    const int node16 = l & 15;
    const int o0 = l & 15;                    // B n-index (tile 0); tile 1 = +16

    f32x4 accN0 = {0.f, 0.f, 0.f, 0.f}, accN1 = {0.f, 0.f, 0.f, 0.f};
    f32x4 accR0 = {0.f, 0.f, 0.f, 0.f}, accR1 = {0.f, 0.f, 0.f, 0.f};

    #pragma unroll
    for (int j = 0; j < 6; j++) {
        const int rr = w + 8 * j;             // wave-uniform
        if (rr < KROWS) {
            const unsigned short* Bsrc = (rr < 33) ? (WBs + (size_t)rr * 1024)
                                                   : (WBl + (size_t)(rr - 33) * 1024);
            short8 bf0 = *(const short8*)(Bsrc + o0 * 32 + quad * 8);
            short8 bf1 = *(const short8*)(Bsrc + (o0 + 16) * 32 + quad * 8);
            short8 a = *(const short8*)&P_lds[node16][rr][quad * 8];
            if (rr <= 32 || rr == 42) {
                accN0 = __builtin_amdgcn_mfma_f32_16x16x32_bf16(a, bf0, accN0, 0, 0, 0);
                accN1 = __builtin_amdgcn_mfma_f32_16x16x32_bf16(a, bf1, accN1, 0, 0, 0);
            } else {
                accR0 = __builtin_amdgcn_mfma_f32_16x16x32_bf16(a, bf0, accR0, 0, 0, 0);
                accR1 = __builtin_amdgcn_mfma_f32_16x16x32_bf16(a, bf1, accR1, 0, 0, 0);
            }
        }
    }
    __syncthreads();                          // all A-reads done; safe to overlay RedAll

    // ---------- deterministic cross-wave reduction (no atomics) ----------
    float* RedAll = (float*)&P_lds[0][0][0];  // 8 waves x 1024 floats = 32 KiB < 44 KiB
    {
        float* my = RedAll + w * 1024;
        #pragma unroll
        for (int reg = 0; reg < 4; reg++) {
            int nd = quad * 4 + reg;          // C/D: row(m=node)=quad*4+reg, col(n=o)=lane&15
            my[nd * 32 + o0]            = accN0[reg];
            my[nd * 32 + o0 + 16]       = accN1[reg];
            my[512 + nd * 32 + o0]      = accR0[reg];
            my[512 + nd * 32 + o0 + 16] = accR1[reg];
        }
    }
    __syncthreads();

    // ---------- epilogue (node slot = hw, output col = lane) ----------
    {
        const int hw2 = tid >> 5, lane = tid & 31;
        const int n2 = n0 + hw2;
        float sn = 0.0f, sr = 0.0f;
        #pragma unroll
        for (int ww = 0; ww < 8; ww++) {
            sn += RedAll[ww * 1024 + tid];          // stride-1, conflict-free
            sr += RedAll[ww * 1024 + 512 + tid];
        }
        float hd = h[n2 * EMB + lane];
        float o_r = fmaxf(sr + rgcnBias_l[lane], 0.0f);
        float o_n = fmaxf(sn + nnBias_l[lane], 0.0f);
        hout[n2 * EMB + lane] = hd + o_r + o_n;
    }
}

// ---------------- launch ----------------

extern "C" void kernel_launch(void* const* d_in, const int* in_sizes, int n_in,
                              void* d_out, int out_size, void* d_ws, size_t ws_size,
                              hipStream_t stream) {
    const float* x        = (const float*)d_in[0];
    const int*   ei       = (const int*)d_in[1];
    const int*   et       = (const int*)d_in[2];
    const float* ed       = (const float*)d_in[3];
    const float* fcW      = (const float*)d_in[4];
    const float* fcb      = (const float*)d_in[5];
    const float* rgcnW    = (const float*)d_in[6];
    const float* rgcnRoot = (const float*)d_in[7];
    const float* rgcnBias = (const float*)d_in[8];
    const float* W1       = (const float*)d_in[9];
    const float* b1       = (const float*)d_in[10];
    const float* W2       = (const float*)d_in[11];
    const float* b2       = (const float*)d_in[12];
    const float* nnRoot   = (const float*)d_in[13];
    const float* nnBias   = (const float*)d_in[14];

    float* ws = (float*)d_ws;
    float* h_a    = ws;  ws += (size_t)N_NODES * EMB;
    float* h_b    = ws;  ws += (size_t)N_NODES * EMB;
    float* invdeg = ws;  ws += (size_t)N_NODES;
    float* invcnt = ws;  ws += (size_t)N_NODES * NREL;
    unsigned short* WB = (unsigned short*)ws;  ws += (size_t)83 * 1024 / 2;  // 83 rows bf16
    int2* edge2   = (int2*)ws;     ws += (size_t)N_EDGES * 2;
    int* row_ptr  = (int*)ws;      ws += (size_t)(N_NODES + 1);
    int* bsum     = (int*)ws;      ws += (size_t)NCHUNK;
    int* boff     = (int*)ws;      ws += (size_t)NCHUNK;
    int* deg      = (int*)ws;      ws += (size_t)N_NODES;       // deg..cursor contiguous (zeroed)
    int* relcnt   = (int*)ws;      ws += (size_t)N_NODES * NREL;
    int* cursor   = (int*)ws;      ws += (size_t)N_NODES;
    (void)in_sizes; (void)n_in; (void)out_size; (void)ws_size;

    zero_kernel<<<(10 * N_NODES + 255) / 256, 256, 0, stream>>>(deg, 10 * N_NODES);
    hist_kernel<<<(N_EDGES + 255) / 256, 256, 0, stream>>>(ei, et, deg, relcnt);
    bsum_kernel<<<NCHUNK, 256, 0, stream>>>(deg, bsum);
    inv_kernel<<<(N_NODES + 255) / 256, 256, 0, stream>>>(deg, relcnt, invdeg, invcnt);
    boff_kernel<<<1, 256, 0, stream>>>(bsum, boff, row_ptr);
    rptr_kernel<<<NCHUNK, 256, 0, stream>>>(deg, boff, row_ptr);
    scatter_kernel<<<(N_EDGES + 255) / 256, 256, 0, stream>>>(ei, et, ed, row_ptr,
                                                              cursor, edge2);
    wtbf_kernel<<<83, 256, 0, stream>>>(W2, b2, rgcnW, rgcnRoot, nnRoot, WB);
    fc_kernel<<<N_NODES / 8, 256, 0, stream>>>(x, fcW, fcb, h_a);

    const float* hin = h_a;
    float* houtb = h_b;
    for (int l = 0; l < NLAYER; l++) {
        float* dst = (l == NLAYER - 1) ? (float*)d_out : houtb;
        layer_kernel<<<N_NODES / NPB, 512, 0, stream>>>(
            hin, edge2, row_ptr, invdeg, invcnt, W1, b1,
            WB, WB + (size_t)(33 + l * 10) * 1024,
            rgcnBias + (size_t)l * EMB,
            nnBias + (size_t)l * EMB,
            dst);
        float* old_in = (float*)hin;
        hin = dst;
        houtb = old_in;
    }
}

// Round 2
// 434.572 us; speedup vs baseline: 1.0654x; 1.0425x over previous
//
#include <hip/hip_runtime.h>

#define N_NODES 50000
#define N_EDGES 400000
#define EMB 32
#define NREL 8
#define NLAYER 5
#define NPB 16          // nodes per block (8 waves x 2 sequential passes)
#define KROWS 43        // 0..31 P, 32 Stot, 33..40 S_r, 41 h_dst(rgcnRoot), 42 h_dst(nnRoot)
#define NCHUNK 196      // ceil(50000/256) scan chunks

typedef __attribute__((ext_vector_type(8))) short short8;   // 8 bf16 (4 VGPRs)
typedef __attribute__((ext_vector_type(4))) float f32x4;    // MFMA accumulator
typedef __attribute__((ext_vector_type(4))) unsigned int u32x4v;

__device__ __forceinline__ unsigned short f2bf(float f) {   // RNE f32 -> bf16
    unsigned u = __float_as_uint(f);
    unsigned r = u + 0x7FFF + ((u >> 16) & 1);
    return (unsigned short)(r >> 16);
}

// packed RNE f32x2 -> bf16x2 (lo = a, hi = b)
__device__ __forceinline__ unsigned cvt_pk(float a, float b) {
    unsigned r;
    asm("v_cvt_pk_bf16_f32 %0, %1, %2" : "=v"(r) : "v"(a), "v"(b));
    return r;
}

// ---------------- setup kernels ----------------

__global__ __launch_bounds__(256) void zero_kernel(int* __restrict__ p, int n) {
    int i = blockIdx.x * 256 + threadIdx.x;
    if (i < n) p[i] = 0;
}

__global__ __launch_bounds__(256) void hist_kernel(const int* __restrict__ ei,
                                                   const int* __restrict__ et,
                                                   int* __restrict__ deg,
                                                   int* __restrict__ relcnt) {
    int e = blockIdx.x * 256 + threadIdx.x;
    if (e < N_EDGES) {
        int d = ei[N_EDGES + e];           // dst = edge_index[1]
        atomicAdd(&deg[d], 1);
        atomicAdd(&relcnt[d * NREL + et[e]], 1);
    }
}

// per-chunk sum of deg
__global__ __launch_bounds__(256) void bsum_kernel(const int* __restrict__ deg,
                                                   int* __restrict__ bsum) {
    __shared__ int wsum[4];
    int tid = threadIdx.x, lane = tid & 63, w = tid >> 6;
    int i = blockIdx.x * 256 + tid;
    int v = (i < N_NODES) ? deg[i] : 0;
    #pragma unroll
    for (int off = 32; off > 0; off >>= 1) v += __shfl_down(v, off, 64);
    if (lane == 0) wsum[w] = v;
    __syncthreads();
    if (tid == 0) bsum[blockIdx.x] = wsum[0] + wsum[1] + wsum[2] + wsum[3];
}

// scan chunk sums -> boff; row_ptr[N]=E
__global__ __launch_bounds__(256) void boff_kernel(const int* __restrict__ bsum,
                                                   int* __restrict__ boff,
                                                   int* __restrict__ row_ptr) {
    __shared__ int ws[4];
    int tid = threadIdx.x, lane = tid & 63, w = tid >> 6;
    int v = (tid < NCHUNK) ? bsum[tid] : 0;
    int incl = v;
    #pragma unroll
    for (int off = 1; off < 64; off <<= 1) {
        int t = __shfl_up(incl, off, 64);
        if (lane >= off) incl += t;
    }
    if (lane == 63) ws[w] = incl;
    __syncthreads();
    int add = 0;
    for (int j = 0; j < w; j++) add += ws[j];
    if (tid < NCHUNK) boff[tid] = add + incl - v;
    if (tid == 0) row_ptr[N_NODES] = N_EDGES;
}

// per-chunk exclusive scan + chunk offset -> row_ptr
__global__ __launch_bounds__(256) void rptr_kernel(const int* __restrict__ deg,
                                                   const int* __restrict__ boff,
                                                   int* __restrict__ row_ptr) {
    __shared__ int ws[4];
    int tid = threadIdx.x, lane = tid & 63, w = tid >> 6;
    int i = blockIdx.x * 256 + tid;
    int v = (i < N_NODES) ? deg[i] : 0;
    int incl = v;
    #pragma unroll
    for (int off = 1; off < 64; off <<= 1) {
        int t = __shfl_up(incl, off, 64);
        if (lane >= off) incl += t;
    }
    if (lane == 63) ws[w] = incl;
    __syncthreads();
    int add = boff[blockIdx.x];
    for (int j = 0; j < w; j++) add += ws[j];
    if (i < N_NODES) row_ptr[i] = add + incl - v;
}

__global__ __launch_bounds__(256) void inv_kernel(const int* __restrict__ deg,
                                                  const int* __restrict__ relcnt,
                                                  float* __restrict__ invdeg,
                                                  float* __restrict__ invcnt) {
    int n = blockIdx.x * 256 + threadIdx.x;
    if (n < N_NODES) {
        int d = deg[n];
        invdeg[n] = 1.0f / (float)(d > 0 ? d : 1);
        #pragma unroll
        for (int r = 0; r < NREL; r++) {
            int c = relcnt[n * NREL + r];
            invcnt[n * NREL + r] = 1.0f / (float)(c > 0 ? c : 1);
        }
    }
}

__global__ __launch_bounds__(256) void scatter_kernel(const int* __restrict__ ei,
                                                      const int* __restrict__ et,
                                                      const float* __restrict__ ed,
                                                      const int* __restrict__ row_ptr,
                                                      int* __restrict__ cursor,
                                                      int2* __restrict__ edge2) {
    int e = blockIdx.x * 256 + threadIdx.x;
    if (e < N_EDGES) {
        int d = ei[N_EDGES + e];
        int pos = row_ptr[d] + atomicAdd(&cursor[d], 1);
        edge2[pos] = make_int2(ei[e] | (et[e] << 16), __float_as_int(ed[e]));
    }
}

// transpose+bf16 contraction weights with interleaved-k permutation:
//   k-slot k holds input index i(k) = (k>>1) + ((k&1)<<4)
//   WB[m][o*32+k] = bf16(src_m[i(k)*32 + o])
// m 0..31: W2 rows; 32: b2; 33+l*10+j: j<8 rgcnW[l][j], j==8 rgcnRoot[l], j==9 nnRoot[l]
__global__ __launch_bounds__(256) void wtbf_kernel(const float* __restrict__ W2,
                                                   const float* __restrict__ b2,
                                                   const float* __restrict__ rgcnW,
                                                   const float* __restrict__ rgcnRoot,
                                                   const float* __restrict__ nnRoot,
                                                   unsigned short* __restrict__ WB) {
    int m = blockIdx.x;
    const float* src;
    if (m < 32) src = W2 + (size_t)m * 1024;
    else if (m == 32) src = b2;
    else {
        int t = m - 33, l = t / 10, j = t % 10;
        src = (j < 8) ? rgcnW + (size_t)(l * 8 + j) * 1024
            : (j == 8) ? rgcnRoot + (size_t)l * 1024
                       : nnRoot + (size_t)l * 1024;
    }
    unsigned short* dst = WB + (size_t)m * 1024;
    #pragma unroll
    for (int c = 0; c < 4; c++) {
        int idx = c * 256 + threadIdx.x;
        int o = idx >> 5, k = idx & 31;
        int i = (k >> 1) + ((k & 1) << 4);
        dst[o * 32 + k] = f2bf(src[i * 32 + o]);
    }
}

// ---------------- fc: h0 = relu(x @ fc_W + fc_b) ----------------

__global__ __launch_bounds__(256) void fc_kernel(const float* __restrict__ x,
                                                 const float* __restrict__ W,
                                                 const float* __restrict__ b,
                                                 float* __restrict__ h) {
    __shared__ __align__(16) float xt[8][EMB];
    int tid = threadIdx.x;
    int nl = tid >> 5, lane = tid & 31;
    int n0 = blockIdx.x * 8;
    xt[tid >> 5][tid & 31] = x[n0 * EMB + tid];
    __syncthreads();
    float acc = b[lane];
    #pragma unroll
    for (int i = 0; i < EMB; i++) acc += xt[nl][i] * W[i * EMB + lane];
    h[(n0 + nl) * EMB + lane] = fmaxf(acc, 0.0f);
}

// ---------------- fused layer kernel (MFMA edge phase + MFMA contraction) ----------------
// Edge phase: one wave per node, 2 sequential node passes per wave (16 nodes/block).
// Per node: G[41,32] = Coef[41,E_n] x Hsrc[E_n,32] as K=32-edge MFMA chunks.
// k-slot map (WAVE-UNIFORM skip): k = quad*8 + 2jp + b  <->  edge = c0 + jp*8 + quad*2 + b.
// jp-block j covers edges [c0+8j, c0+8j+8) for ALL quads -> guard `c0+jp*8 < pe` is
// wave-uniform; deg<=8 nodes execute exactly 1 of 4 statically-unrolled jp bodies
// (mean trips ~1.42 vs 4.0 before). Fragments zero-init so skipped slots contribute 0.
// A-fragment: row = lane&15, k = (lane>>4)*8 + j.  D: row = (lane>>4)*4 + reg, col = lane&15.
// Staged A columns use interleaved order col' = 2m (i=m) / 2m+1 (i=m+16) so each
// LDS store is one packed cvt_pk b32 write; WB k-order is permuted to match.
__global__ __launch_bounds__(512, 6) void layer_kernel(
    const float* __restrict__ h,
    const int2* __restrict__ edge2,
    const int* __restrict__ row_ptr,
    const float* __restrict__ invdeg,
    const float* __restrict__ invcnt,
    const float* __restrict__ W1,
    const float* __restrict__ b1,
    const unsigned short* __restrict__ WBs,   // rows 0..32 (W2^T, b2^T)
    const unsigned short* __restrict__ WBl,   // rows 33..42 (rgcnW^T x8, rgcnRoot^T, nnRoot^T)
    const float* __restrict__ rgcnBias_l,
    const float* __restrict__ nnBias_l,
    float* __restrict__ hout)
{
    __shared__ __align__(16) unsigned short P_lds[NPB][KROWS][EMB];  // 44032 B
    __shared__ __align__(16) float wrb2[NREL][32];                   // [r][2m+half] = W1[1+r][m+16*half]+b1
    // total 45056 B -> 3 blocks/CU

    const int tid = threadIdx.x;
    const int n0 = blockIdx.x * NPB;

    // stage per-relation hid constants: wrb2[r][2m]   = W1[1+r][m]    + b1[m]
    //                                   wrb2[r][2m+1] = W1[1+r][m+16] + b1[m+16]
    if (tid < 256) {
        int r = tid >> 5, i = tid & 31;
        int mm = (i >> 1) + ((i & 1) << 4);
        wrb2[r][i] = W1[(1 + r) * EMB + mm] + b1[mm];
    }

    const int l    = tid & 63;
    const int w    = tid >> 6;        // wave 0..7
    const int quad = l >> 4;          // 0..3
    const int m    = l & 15;
    const float w10_0 = W1[m];        // W1[0][m]
    const float w10_1 = W1[m + 16];   // W1[0][m+16]

    // preload both passes' row bounds + first edge pair (overlap the load chains)
    int pbA[2], peA[2];
    pbA[0] = row_ptr[n0 + w];      peA[0] = row_ptr[n0 + w + 1];
    pbA[1] = row_ptr[n0 + 8 + w];  peA[1] = row_ptr[n0 + 8 + w + 1];
    int2 eApre[2], eBpre[2];
    #pragma unroll
    for (int p = 0; p < 2; ++p) {
        const int2* ep = edge2 + pbA[p] + quad * 2;   // harmless OOB-read if empty (ws-mapped)
        eApre[p] = ep[0]; eBpre[p] = ep[1];
    }

    __syncthreads();   // wrb2 ready

    // per-edge-pair fragment builder: k-slots (2jp, 2jp+1) of this quad
#define EDGE_PAIR(ea, eb, va, vb, A0, A1, AS, B0, B1) do {                        \
        int ra = ((ea).x >> 16) & 7, rb = ((eb).x >> 16) & 7;                     \
        float2 wa = *(const float2*)&wrb2[ra][2 * m];                             \
        float2 wb = *(const float2*)&wrb2[rb][2 * m];                             \
        float da = __int_as_float((ea).y), db = __int_as_float((eb).y);           \
        float hA0 = (va) ? fmaxf(fmaf(da, w10_0, wa.x), 0.f) : 0.f;               \
        float hA1 = (va) ? fmaxf(fmaf(da, w10_1, wa.y), 0.f) : 0.f;               \
        float hB0 = (vb) ? fmaxf(fmaf(db, w10_0, wb.x), 0.f) : 0.f;               \
        float hB1 = (vb) ? fmaxf(fmaf(db, w10_1, wb.y), 0.f) : 0.f;               \
        A0 = cvt_pk(hA0, hB0);                                                    \
        A1 = cvt_pk(hA1, hB1);                                                    \
        float sA = ((va) && (m == 0 || ra == m - 1)) ? 1.f : 0.f;                 \
        float sB = ((vb) && (m == 0 || rb == m - 1)) ? 1.f : 0.f;                 \
        AS = cvt_pk(sA, sB);                                                      \
        int offa = (va) ? (((ea).x & 0xFFFF) << 5) + m : m;                       \
        int offb = (vb) ? (((eb).x & 0xFFFF) << 5) + m : m;                       \
        float bA0 = h[offa], bA1 = h[offa + 16];                                  \
        float bB0 = h[offb], bB1 = h[offb + 16];                                  \
        B0 = cvt_pk(bA0, bB0);                                                    \
        B1 = cvt_pk(bA1, bB1);                                                    \
    } while (0)

    #pragma unroll
    for (int pass = 0; pass < 2; ++pass) {
        const int hw = w + pass * 8;          // node slot 0..15
        const int n  = n0 + hw;
        const int pb = pbA[pass], pe = peA[pass];

        f32x4 aP00 = {0.f, 0.f, 0.f, 0.f}, aP01 = {0.f, 0.f, 0.f, 0.f};
        f32x4 aP10 = {0.f, 0.f, 0.f, 0.f}, aP11 = {0.f, 0.f, 0.f, 0.f};
        f32x4 aS0  = {0.f, 0.f, 0.f, 0.f}, aS1  = {0.f, 0.f, 0.f, 0.f};

        for (int c0 = pb; c0 < pe; c0 += 32) {
            u32x4v fa0 = {0,0,0,0}, fa1 = {0,0,0,0}, fas = {0,0,0,0};
            u32x4v fb0 = {0,0,0,0}, fb1 = {0,0,0,0};

            {   // jp = 0 (always executed when chunk exists; first chunk uses preload)
                const int ebs = c0 + quad * 2;
                int2 ea, eb;
                if (c0 == pb) { ea = eApre[pass]; eb = eBpre[pass]; }
                else          { ea = edge2[ebs];  eb = edge2[ebs + 1]; }
                EDGE_PAIR(ea, eb, ebs < pe, ebs + 1 < pe,
                          fa0[0], fa1[0], fas[0], fb0[0], fb1[0]);
            }
            #pragma unroll
            for (int jp = 1; jp < 4; ++jp) {
                if (c0 + jp * 8 < pe) {       // WAVE-UNIFORM guard
                    const int ebs = c0 + jp * 8 + quad * 2;
                    int2 ea = edge2[ebs], eb = edge2[ebs + 1];
                    EDGE_PAIR(ea, eb, ebs < pe, ebs + 1 < pe,
                              fa0[jp], fa1[jp], fas[jp], fb0[jp], fb1[jp]);
                }
            }

            short8 A0 = __builtin_bit_cast(short8, fa0);
            short8 A1 = __builtin_bit_cast(short8, fa1);
            short8 AS = __builtin_bit_cast(short8, fas);
            short8 B0 = __builtin_bit_cast(short8, fb0);
            short8 B1 = __builtin_bit_cast(short8, fb1);
            aP00 = __builtin_amdgcn_mfma_f32_16x16x32_bf16(A0, B0, aP00, 0, 0, 0);
            aP01 = __builtin_amdgcn_mfma_f32_16x16x32_bf16(A0, B1, aP01, 0, 0, 0);
            aP10 = __builtin_amdgcn_mfma_f32_16x16x32_bf16(A1, B0, aP10, 0, 0, 0);
            aP11 = __builtin_amdgcn_mfma_f32_16x16x32_bf16(A1, B1, aP11, 0, 0, 0);
            aS0  = __builtin_amdgcn_mfma_f32_16x16x32_bf16(AS, B0, aS0, 0, 0, 0);
            aS1  = __builtin_amdgcn_mfma_f32_16x16x32_bf16(AS, B1, aS1, 0, 0, 0);
        }

        // ---------- stage bf16 A-rows, pre-scaled (packed b32 writes) ----------
        const float idg = invdeg[n];
        #pragma unroll
        for (int reg = 0; reg < 4; ++reg) {
            const int row = quad * 4 + reg;   // D row within tile
            *(unsigned*)&P_lds[hw][row][2 * m] =
                cvt_pk(aP00[reg] * idg, aP01[reg] * idg);
            *(unsigned*)&P_lds[hw][row + 16][2 * m] =
                cvt_pk(aP10[reg] * idg, aP11[reg] * idg);
            if (row <= 8) {                   // S rows: 0 -> Stot(32), 1..8 -> S_r(33..40)
                const float sc = (row == 0) ? idg : invcnt[n * NREL + row - 1];
                *(unsigned*)&P_lds[hw][32 + row][2 * m] =
                    cvt_pk(aS0[reg] * sc, aS1[reg] * sc);
            }
        }
        if (quad < 2) {                       // rows 41 (rgcnRoot) / 42 (nnRoot): h_dst
            float h0 = h[n * EMB + m], h1 = h[n * EMB + m + 16];
            *(unsigned*)&P_lds[hw][41 + quad][2 * m] = cvt_pk(h0, h1);
        }
    }
#undef EDGE_PAIR
    __syncthreads();

    // ---------- MFMA contraction (unchanged; WB k-order matches staged columns) ----------
    const int node16 = l & 15;
    const int o0 = l & 15;                    // B n-index (tile 0); tile 1 = +16

    f32x4 accN0 = {0.f, 0.f, 0.f, 0.f}, accN1 = {0.f, 0.f, 0.f, 0.f};
    f32x4 accR0 = {0.f, 0.f, 0.f, 0.f}, accR1 = {0.f, 0.f, 0.f, 0.f};

    #pragma unroll
    for (int j = 0; j < 6; j++) {
        const int rr = w + 8 * j;             // wave-uniform
        if (rr < KROWS) {
            const unsigned short* Bsrc = (rr < 33) ? (WBs + (size_t)rr * 1024)
                                                   : (WBl + (size_t)(rr - 33) * 1024);
            short8 bf0 = *(const short8*)(Bsrc + o0 * 32 + quad * 8);
            short8 bf1 = *(const short8*)(Bsrc + (o0 + 16) * 32 + quad * 8);
            short8 a = *(const short8*)&P_lds[node16][rr][quad * 8];
            if (rr <= 32 || rr == 42) {
                accN0 = __builtin_amdgcn_mfma_f32_16x16x32_bf16(a, bf0, accN0, 0, 0, 0);
                accN1 = __builtin_amdgcn_mfma_f32_16x16x32_bf16(a, bf1, accN1, 0, 0, 0);
            } else {
                accR0 = __builtin_amdgcn_mfma_f32_16x16x32_bf16(a, bf0, accR0, 0, 0, 0);
                accR1 = __builtin_amdgcn_mfma_f32_16x16x32_bf16(a, bf1, accR1, 0, 0, 0);
            }
        }
    }
    __syncthreads();                          // all A-reads done; safe to overlay RedAll

    // ---------- deterministic cross-wave reduction (no atomics) ----------
    float* RedAll = (float*)&P_lds[0][0][0];  // 8 waves x 1024 floats = 32 KiB < 44 KiB
    {
        float* my = RedAll + w * 1024;
        #pragma unroll
        for (int reg = 0; reg < 4; reg++) {
            int nd = quad * 4 + reg;          // C/D: row(m=node)=quad*4+reg, col(n=o)=lane&15
            my[nd * 32 + o0]            = accN0[reg];
            my[nd * 32 + o0 + 16]       = accN1[reg];
            my[512 + nd * 32 + o0]      = accR0[reg];
            my[512 + nd * 32 + o0 + 16] = accR1[reg];
        }
    }
    __syncthreads();

    // ---------- epilogue (node slot = hw, output col = lane) ----------
    {
        const int hw2 = tid >> 5, lane = tid & 31;
        const int n2 = n0 + hw2;
        float sn = 0.0f, sr = 0.0f;
        #pragma unroll
        for (int ww = 0; ww < 8; ww++) {
            sn += RedAll[ww * 1024 + tid];          // stride-1, conflict-free
            sr += RedAll[ww * 1024 + 512 + tid];
        }
        float hd = h[n2 * EMB + lane];
        float o_r = fmaxf(sr + rgcnBias_l[lane], 0.0f);
        float o_n = fmaxf(sn + nnBias_l[lane], 0.0f);
        hout[n2 * EMB + lane] = hd + o_r + o_n;
    }
}

// ---------------- launch ----------------

extern "C" void kernel_launch(void* const* d_in, const int* in_sizes, int n_in,
                              void* d_out, int out_size, void* d_ws, size_t ws_size,
                              hipStream_t stream) {
    const float* x        = (const float*)d_in[0];
    const int*   ei       = (const int*)d_in[1];
    const int*   et       = (const int*)d_in[2];
    const float* ed       = (const float*)d_in[3];
    const float* fcW      = (const float*)d_in[4];
    const float* fcb      = (const float*)d_in[5];
    const float* rgcnW    = (const float*)d_in[6];
    const float* rgcnRoot = (const float*)d_in[7];
    const float* rgcnBias = (const float*)d_in[8];
    const float* W1       = (const float*)d_in[9];
    const float* b1       = (const float*)d_in[10];
    const float* W2       = (const float*)d_in[11];
    const float* b2       = (const float*)d_in[12];
    const float* nnRoot   = (const float*)d_in[13];
    const float* nnBias   = (const float*)d_in[14];

    float* ws = (float*)d_ws;
    float* h_a    = ws;  ws += (size_t)N_NODES * EMB;
    float* h_b    = ws;  ws += (size_t)N_NODES * EMB;
    float* invdeg = ws;  ws += (size_t)N_NODES;
    float* invcnt = ws;  ws += (size_t)N_NODES * NREL;
    unsigned short* WB = (unsigned short*)ws;  ws += (size_t)83 * 1024 / 2;  // 83 rows bf16
    int2* edge2   = (int2*)ws;     ws += (size_t)N_EDGES * 2;
    int* row_ptr  = (int*)ws;      ws += (size_t)(N_NODES + 1);
    int* bsum     = (int*)ws;      ws += (size_t)NCHUNK;
    int* boff     = (int*)ws;      ws += (size_t)NCHUNK;
    int* deg      = (int*)ws;      ws += (size_t)N_NODES;       // deg..cursor contiguous (zeroed)
    int* relcnt   = (int*)ws;      ws += (size_t)N_NODES * NREL;
    int* cursor   = (int*)ws;      ws += (size_t)N_NODES;
    (void)in_sizes; (void)n_in; (void)out_size; (void)ws_size;

    zero_kernel<<<(10 * N_NODES + 255) / 256, 256, 0, stream>>>(deg, 10 * N_NODES);
    hist_kernel<<<(N_EDGES + 255) / 256, 256, 0, stream>>>(ei, et, deg, relcnt);
    bsum_kernel<<<NCHUNK, 256, 0, stream>>>(deg, bsum);
    inv_kernel<<<(N_NODES + 255) / 256, 256, 0, stream>>>(deg, relcnt, invdeg, invcnt);
    boff_kernel<<<1, 256, 0, stream>>>(bsum, boff, row_ptr);
    rptr_kernel<<<NCHUNK, 256, 0, stream>>>(deg, boff, row_ptr);
    scatter_kernel<<<(N_EDGES + 255) / 256, 256, 0, stream>>>(ei, et, ed, row_ptr,
                                                              cursor, edge2);
    wtbf_kernel<<<83, 256, 0, stream>>>(W2, b2, rgcnW, rgcnRoot, nnRoot, WB);
    fc_kernel<<<N_NODES / 8, 256, 0, stream>>>(x, fcW, fcb, h_a);

    const float* hin = h_a;
    float* houtb = h_b;
    for (int l = 0; l < NLAYER; l++) {
        float* dst = (l == NLAYER - 1) ? (float*)d_out : houtb;
        layer_kernel<<<N_NODES / NPB, 512, 0, stream>>>(
            hin, edge2, row_ptr, invdeg, invcnt, W1, b1,
            WB, WB + (size_t)(33 + l * 10) * 1024,
            rgcnBias + (size_t)l * EMB,
            nnBias + (size_t)l * EMB,
            dst);
        float* old_in = (float*)hin;
        hin = dst;
        houtb = old_in;
    }
}

// Round 3
// 422.700 us; speedup vs baseline: 1.0953x; 1.0281x over previous
//
#include <hip/hip_runtime.h>

#define N_NODES 50000
#define N_EDGES 400000
#define EMB 32
#define NREL 8
#define NLAYER 5
#define NPB 16          // nodes per block (8 waves x 2 balanced passes)
#define NBLK (N_NODES / NPB)   // 3125 node-blocks
#define KROWS 43        // 0..31 P, 32 Stot, 33..40 S_r, 41 h_dst(rgcnRoot), 42 h_dst(nnRoot)
#define NCHUNK 196      // ceil(50000/256) scan chunks

typedef __attribute__((ext_vector_type(8))) short short8;   // 8 bf16 (4 VGPRs)
typedef __attribute__((ext_vector_type(4))) float f32x4;    // MFMA accumulator
typedef __attribute__((ext_vector_type(4))) unsigned int u32x4v;

__device__ __forceinline__ unsigned short f2bf(float f) {   // RNE f32 -> bf16
    unsigned u = __float_as_uint(f);
    unsigned r = u + 0x7FFF + ((u >> 16) & 1);
    return (unsigned short)(r >> 16);
}

// packed RNE f32x2 -> bf16x2 (lo = a, hi = b)
__device__ __forceinline__ unsigned cvt_pk(float a, float b) {
    unsigned r;
    asm("v_cvt_pk_bf16_f32 %0, %1, %2" : "=v"(r) : "v"(a), "v"(b));
    return r;
}

// ---------------- setup kernels ----------------

__global__ __launch_bounds__(256) void zero_kernel(int* __restrict__ p, int n) {
    int i = blockIdx.x * 256 + threadIdx.x;
    if (i < n) p[i] = 0;
}

__global__ __launch_bounds__(256) void hist_kernel(const int* __restrict__ ei,
                                                   const int* __restrict__ et,
                                                   int* __restrict__ deg,
                                                   int* __restrict__ relcnt) {
    int e = blockIdx.x * 256 + threadIdx.x;
    if (e < N_EDGES) {
        int d = ei[N_EDGES + e];           // dst = edge_index[1]
        atomicAdd(&deg[d], 1);
        atomicAdd(&relcnt[d * NREL + et[e]], 1);
    }
}

// per-chunk sum of deg
__global__ __launch_bounds__(256) void bsum_kernel(const int* __restrict__ deg,
                                                   int* __restrict__ bsum) {
    __shared__ int wsum[4];
    int tid = threadIdx.x, lane = tid & 63, w = tid >> 6;
    int i = blockIdx.x * 256 + tid;
    int v = (i < N_NODES) ? deg[i] : 0;
    #pragma unroll
    for (int off = 32; off > 0; off >>= 1) v += __shfl_down(v, off, 64);
    if (lane == 0) wsum[w] = v;
    __syncthreads();
    if (tid == 0) bsum[blockIdx.x] = wsum[0] + wsum[1] + wsum[2] + wsum[3];
}

// scan chunk sums -> boff; row_ptr[N]=E
__global__ __launch_bounds__(256) void boff_kernel(const int* __restrict__ bsum,
                                                   int* __restrict__ boff,
                                                   int* __restrict__ row_ptr) {
    __shared__ int ws[4];
    int tid = threadIdx.x, lane = tid & 63, w = tid >> 6;
    int v = (tid < NCHUNK) ? bsum[tid] : 0;
    int incl = v;
    #pragma unroll
    for (int off = 1; off < 64; off <<= 1) {
        int t = __shfl_up(incl, off, 64);
        if (lane >= off) incl += t;
    }
    if (lane == 63) ws[w] = incl;
    __syncthreads();
    int add = 0;
    for (int j = 0; j < w; j++) add += ws[j];
    if (tid < NCHUNK) boff[tid] = add + incl - v;
    if (tid == 0) row_ptr[N_NODES] = N_EDGES;
}

// per-chunk exclusive scan + chunk offset -> row_ptr
__global__ __launch_bounds__(256) void rptr_kernel(const int* __restrict__ deg,
                                                   const int* __restrict__ boff,
                                                   int* __restrict__ row_ptr) {
    __shared__ int ws[4];
    int tid = threadIdx.x, lane = tid & 63, w = tid >> 6;
    int i = blockIdx.x * 256 + tid;
    int v = (i < N_NODES) ? deg[i] : 0;
    int incl = v;
    #pragma unroll
    for (int off = 1; off < 64; off <<= 1) {
        int t = __shfl_up(incl, off, 64);
        if (lane >= off) incl += t;
    }
    if (lane == 63) ws[w] = incl;
    __syncthreads();
    int add = boff[blockIdx.x];
    for (int j = 0; j < w; j++) add += ws[j];
    if (i < N_NODES) row_ptr[i] = add + incl - v;
}

__global__ __launch_bounds__(256) void inv_kernel(const int* __restrict__ deg,
                                                  const int* __restrict__ relcnt,
                                                  float* __restrict__ invdeg,
                                                  float* __restrict__ invcnt) {
    int n = blockIdx.x * 256 + threadIdx.x;
    if (n < N_NODES) {
        int d = deg[n];
        invdeg[n] = 1.0f / (float)(d > 0 ? d : 1);
        #pragma unroll
        for (int r = 0; r < NREL; r++) {
            int c = relcnt[n * NREL + r];
            invcnt[n * NREL + r] = 1.0f / (float)(c > 0 ? c : 1);
        }
    }
}

// per-block degree-balanced wave->slot pairing: sort 16 slots by deg desc;
// wave w takes rank[w] (pass 0) and rank[15-w] (pass 1)  => per-wave edge
// totals ~= mean, not max (kills the pre-contraction barrier tail).
__global__ __launch_bounds__(256) void pairperm_kernel(const int* __restrict__ deg,
                                                       unsigned char* __restrict__ perm) {
    int b = blockIdx.x * 256 + threadIdx.x;
    if (b >= NBLK) return;
    int d[NPB]; unsigned char idx[NPB];
    #pragma unroll
    for (int i = 0; i < NPB; i++) { d[i] = deg[b * NPB + i]; idx[i] = (unsigned char)i; }
    for (int i = 1; i < NPB; i++) {          // insertion sort, desc, stable
        int dv = d[i]; unsigned char iv = idx[i];
        int j = i - 1;
        while (j >= 0 && d[j] < dv) { d[j + 1] = d[j]; idx[j + 1] = idx[j]; j--; }
        d[j + 1] = dv; idx[j + 1] = iv;
    }
    #pragma unroll
    for (int i = 0; i < NPB; i++) perm[b * NPB + i] = idx[i];
}

__global__ __launch_bounds__(256) void scatter_kernel(const int* __restrict__ ei,
                                                      const int* __restrict__ et,
                                                      const float* __restrict__ ed,
                                                      const int* __restrict__ row_ptr,
                                                      int* __restrict__ cursor,
                                                      int2* __restrict__ edge2) {
    int e = blockIdx.x * 256 + threadIdx.x;
    if (e < N_EDGES) {
        int d = ei[N_EDGES + e];
        int pos = row_ptr[d] + atomicAdd(&cursor[d], 1);
        edge2[pos] = make_int2(ei[e] | (et[e] << 16), __float_as_int(ed[e]));
    }
}

// transpose+bf16 contraction weights with interleaved-k permutation:
//   k-slot k holds input index i(k) = (k>>1) + ((k&1)<<4)
//   WB[m][o*32+k] = bf16(src_m[i(k)*32 + o])
// m 0..31: W2 rows; 32: b2; 33+l*10+j: j<8 rgcnW[l][j], j==8 rgcnRoot[l], j==9 nnRoot[l]
__global__ __launch_bounds__(256) void wtbf_kernel(const float* __restrict__ W2,
                                                   const float* __restrict__ b2,
                                                   const float* __restrict__ rgcnW,
                                                   const float* __restrict__ rgcnRoot,
                                                   const float* __restrict__ nnRoot,
                                                   unsigned short* __restrict__ WB) {
    int m = blockIdx.x;
    const float* src;
    if (m < 32) src = W2 + (size_t)m * 1024;
    else if (m == 32) src = b2;
    else {
        int t = m - 33, l = t / 10, j = t % 10;
        src = (j < 8) ? rgcnW + (size_t)(l * 8 + j) * 1024
            : (j == 8) ? rgcnRoot + (size_t)l * 1024
                       : nnRoot + (size_t)l * 1024;
    }
    unsigned short* dst = WB + (size_t)m * 1024;
    #pragma unroll
    for (int c = 0; c < 4; c++) {
        int idx = c * 256 + threadIdx.x;
        int o = idx >> 5, k = idx & 31;
        int i = (k >> 1) + ((k & 1) << 4);
        dst[o * 32 + k] = f2bf(src[i * 32 + o]);
    }
}

// ---------------- fc: h0 = relu(x @ fc_W + fc_b) ----------------

__global__ __launch_bounds__(256) void fc_kernel(const float* __restrict__ x,
                                                 const float* __restrict__ W,
                                                 const float* __restrict__ b,
                                                 float* __restrict__ h) {
    __shared__ __align__(16) float xt[8][EMB];
    int tid = threadIdx.x;
    int nl = tid >> 5, lane = tid & 31;
    int n0 = blockIdx.x * 8;
    xt[tid >> 5][tid & 31] = x[n0 * EMB + tid];
    __syncthreads();
    float acc = b[lane];
    #pragma unroll
    for (int i = 0; i < EMB; i++) acc += xt[nl][i] * W[i * EMB + lane];
    h[(n0 + nl) * EMB + lane] = fmaxf(acc, 0.0f);
}

// ---------------- fused layer kernel (MFMA edge phase + MFMA contraction) ----------------
// Edge phase: one wave per node-slot, 2 balanced passes (pairperm) per wave.
// Per node: G[41,32] = Coef[41,E_n] x Hsrc[E_n,32] as K=32-edge MFMA chunks.
// k-slot map (WAVE-UNIFORM skip): k = quad*8 + 2jp + b  <->  edge = c0 + jp*8 + quad*2 + b.
// jp-block j covers edges [c0+8j, c0+8j+8) for ALL quads -> guard `c0+jp*8 < pe` is
// wave-uniform; deg<=8 nodes execute exactly 1 of 4 statically-unrolled jp bodies.
// Fragments zero-init so skipped slots contribute 0.
// A-fragment: row = lane&15, k = (lane>>4)*8 + j.  D: row = (lane>>4)*4 + reg, col = lane&15.
// Staged A columns use interleaved order col' = 2m (i=m) / 2m+1 (i=m+16) so each
// LDS store is one packed cvt_pk b32 write; WB k-order is permuted to match.
// NO cross-pass preloads (R2's eApre spilled to scratch: WRITE_SIZE 6.3->37.7MB).
__global__ __launch_bounds__(512, 6) void layer_kernel(
    const float* __restrict__ h,
    const int2* __restrict__ edge2,
    const int* __restrict__ row_ptr,
    const float* __restrict__ invdeg,
    const float* __restrict__ invcnt,
    const unsigned char* __restrict__ pairperm,
    const float* __restrict__ W1,
    const float* __restrict__ b1,
    const unsigned short* __restrict__ WBs,   // rows 0..32 (W2^T, b2^T)
    const unsigned short* __restrict__ WBl,   // rows 33..42 (rgcnW^T x8, rgcnRoot^T, nnRoot^T)
    const float* __restrict__ rgcnBias_l,
    const float* __restrict__ nnBias_l,
    float* __restrict__ hout)
{
    __shared__ __align__(16) unsigned short P_lds[NPB][KROWS][EMB];  // 44032 B
    __shared__ __align__(16) float wrb2[NREL][32];                   // [r][2m+half] = W1[1+r][m+16*half]+b1
    // total 45056 B -> 3 blocks/CU

    const int tid = threadIdx.x;
    const int n0 = blockIdx.x * NPB;

    // stage per-relation hid constants: wrb2[r][2m]   = W1[1+r][m]    + b1[m]
    //                                   wrb2[r][2m+1] = W1[1+r][m+16] + b1[m+16]
    if (tid < 256) {
        int r = tid >> 5, i = tid & 31;
        int mm = (i >> 1) + ((i & 1) << 4);
        wrb2[r][i] = W1[(1 + r) * EMB + mm] + b1[mm];
    }

    const int l    = tid & 63;
    const int w    = tid >> 6;        // wave 0..7
    const int quad = l >> 4;          // 0..3
    const int m    = l & 15;
    const float w10_0 = W1[m];        // W1[0][m]
    const float w10_1 = W1[m + 16];   // W1[0][m+16]
    const unsigned char* bp = pairperm + (size_t)blockIdx.x * NPB;

    __syncthreads();   // wrb2 ready

    // per-edge-pair fragment builder: k-slots (2jp, 2jp+1) of this quad
#define EDGE_PAIR(ea, eb, va, vb, A0, A1, AS, B0, B1) do {                        \
        int ra = ((ea).x >> 16) & 7, rb = ((eb).x >> 16) & 7;                     \
        float2 wa = *(const float2*)&wrb2[ra][2 * m];                             \
        float2 wb = *(const float2*)&wrb2[rb][2 * m];                             \
        float da = __int_as_float((ea).y), db = __int_as_float((eb).y);           \
        float hA0 = (va) ? fmaxf(fmaf(da, w10_0, wa.x), 0.f) : 0.f;               \
        float hA1 = (va) ? fmaxf(fmaf(da, w10_1, wa.y), 0.f) : 0.f;               \
        float hB0 = (vb) ? fmaxf(fmaf(db, w10_0, wb.x), 0.f) : 0.f;               \
        float hB1 = (vb) ? fmaxf(fmaf(db, w10_1, wb.y), 0.f) : 0.f;               \
        A0 = cvt_pk(hA0, hB0);                                                    \
        A1 = cvt_pk(hA1, hB1);                                                    \
        float sA = ((va) && (m == 0 || ra == m - 1)) ? 1.f : 0.f;                 \
        float sB = ((vb) && (m == 0 || rb == m - 1)) ? 1.f : 0.f;                 \
        AS = cvt_pk(sA, sB);                                                      \
        int offa = (va) ? (((ea).x & 0xFFFF) << 5) + m : m;                       \
        int offb = (vb) ? (((eb).x & 0xFFFF) << 5) + m : m;                       \
        float bA0 = h[offa], bA1 = h[offa + 16];                                  \
        float bB0 = h[offb], bB1 = h[offb + 16];                                  \
        B0 = cvt_pk(bA0, bB0);                                                    \
        B1 = cvt_pk(bA1, bB1);                                                    \
    } while (0)

    for (int pass = 0; pass < 2; ++pass) {
        const int hw = bp[pass ? (NPB - 1 - w) : w];   // balanced slot (wave-uniform)
        const int n  = n0 + hw;
        const int pb = row_ptr[n], pe = row_ptr[n + 1];

        f32x4 aP00 = {0.f, 0.f, 0.f, 0.f}, aP01 = {0.f, 0.f, 0.f, 0.f};
        f32x4 aP10 = {0.f, 0.f, 0.f, 0.f}, aP11 = {0.f, 0.f, 0.f, 0.f};
        f32x4 aS0  = {0.f, 0.f, 0.f, 0.f}, aS1  = {0.f, 0.f, 0.f, 0.f};

        for (int c0 = pb; c0 < pe; c0 += 32) {
            u32x4v fa0 = {0,0,0,0}, fa1 = {0,0,0,0}, fas = {0,0,0,0};
            u32x4v fb0 = {0,0,0,0}, fb1 = {0,0,0,0};

            #pragma unroll
            for (int jp = 0; jp < 4; ++jp) {
                if (c0 + jp * 8 < pe) {       // WAVE-UNIFORM guard (jp=0 always true)
                    const int ebs = c0 + jp * 8 + quad * 2;
                    int2 ea = edge2[ebs], eb = edge2[ebs + 1];
                    EDGE_PAIR(ea, eb, ebs < pe, ebs + 1 < pe,
                              fa0[jp], fa1[jp], fas[jp], fb0[jp], fb1[jp]);
                }
            }

            short8 A0 = __builtin_bit_cast(short8, fa0);
            short8 A1 = __builtin_bit_cast(short8, fa1);
            short8 AS = __builtin_bit_cast(short8, fas);
            short8 B0 = __builtin_bit_cast(short8, fb0);
            short8 B1 = __builtin_bit_cast(short8, fb1);
            aP00 = __builtin_amdgcn_mfma_f32_16x16x32_bf16(A0, B0, aP00, 0, 0, 0);
            aP01 = __builtin_amdgcn_mfma_f32_16x16x32_bf16(A0, B1, aP01, 0, 0, 0);
            aP10 = __builtin_amdgcn_mfma_f32_16x16x32_bf16(A1, B0, aP10, 0, 0, 0);
            aP11 = __builtin_amdgcn_mfma_f32_16x16x32_bf16(A1, B1, aP11, 0, 0, 0);
            aS0  = __builtin_amdgcn_mfma_f32_16x16x32_bf16(AS, B0, aS0, 0, 0, 0);
            aS1  = __builtin_amdgcn_mfma_f32_16x16x32_bf16(AS, B1, aS1, 0, 0, 0);
        }

        // ---------- stage bf16 A-rows, pre-scaled (packed b32 writes) ----------
        const float idg = invdeg[n];
        #pragma unroll
        for (int reg = 0; reg < 4; ++reg) {
            const int row = quad * 4 + reg;   // D row within tile
            *(unsigned*)&P_lds[hw][row][2 * m] =
                cvt_pk(aP00[reg] * idg, aP01[reg] * idg);
            *(unsigned*)&P_lds[hw][row + 16][2 * m] =
                cvt_pk(aP10[reg] * idg, aP11[reg] * idg);
            if (row <= 8) {                   // S rows: 0 -> Stot(32), 1..8 -> S_r(33..40)
                const float sc = (row == 0) ? idg : invcnt[n * NREL + row - 1];
                *(unsigned*)&P_lds[hw][32 + row][2 * m] =
                    cvt_pk(aS0[reg] * sc, aS1[reg] * sc);
            }
        }
        if (quad < 2) {                       // rows 41 (rgcnRoot) / 42 (nnRoot): h_dst
            float h0 = h[n * EMB + m], h1 = h[n * EMB + m + 16];
            *(unsigned*)&P_lds[hw][41 + quad][2 * m] = cvt_pk(h0, h1);
        }
    }
#undef EDGE_PAIR
    __syncthreads();

    // ---------- MFMA contraction (unchanged; WB k-order matches staged columns) ----------
    const int node16 = l & 15;
    const int o0 = l & 15;                    // B n-index (tile 0); tile 1 = +16

    f32x4 accN0 = {0.f, 0.f, 0.f, 0.f}, accN1 = {0.f, 0.f, 0.f, 0.f};
    f32x4 accR0 = {0.f, 0.f, 0.f, 0.f}, accR1 = {0.f, 0.f, 0.f, 0.f};

    #pragma unroll
    for (int j = 0; j < 6; j++) {
        const int rr = w + 8 * j;             // wave-uniform
        if (rr < KROWS) {
            const unsigned short* Bsrc = (rr < 33) ? (WBs + (size_t)rr * 1024)
                                                   : (WBl + (size_t)(rr - 33) * 1024);
            short8 bf0 = *(const short8*)(Bsrc + o0 * 32 + quad * 8);
            short8 bf1 = *(const short8*)(Bsrc + (o0 + 16) * 32 + quad * 8);
            short8 a = *(const short8*)&P_lds[node16][rr][quad * 8];
            if (rr <= 32 || rr == 42) {
                accN0 = __builtin_amdgcn_mfma_f32_16x16x32_bf16(a, bf0, accN0, 0, 0, 0);
                accN1 = __builtin_amdgcn_mfma_f32_16x16x32_bf16(a, bf1, accN1, 0, 0, 0);
            } else {
                accR0 = __builtin_amdgcn_mfma_f32_16x16x32_bf16(a, bf0, accR0, 0, 0, 0);
                accR1 = __builtin_amdgcn_mfma_f32_16x16x32_bf16(a, bf1, accR1, 0, 0, 0);
            }
        }
    }
    __syncthreads();                          // all A-reads done; safe to overlay RedAll

    // ---------- deterministic cross-wave reduction (no atomics) ----------
    float* RedAll = (float*)&P_lds[0][0][0];  // 8 waves x 1024 floats = 32 KiB < 44 KiB
    {
        float* my = RedAll + w * 1024;
        #pragma unroll
        for (int reg = 0; reg < 4; reg++) {
            int nd = quad * 4 + reg;          // C/D: row(m=node)=quad*4+reg, col(n=o)=lane&15
            my[nd * 32 + o0]            = accN0[reg];
            my[nd * 32 + o0 + 16]       = accN1[reg];
            my[512 + nd * 32 + o0]      = accR0[reg];
            my[512 + nd * 32 + o0 + 16] = accR1[reg];
        }
    }
    __syncthreads();

    // ---------- epilogue (node slot = hw, output col = lane) ----------
    {
        const int hw2 = tid >> 5, lane = tid & 31;
        const int n2 = n0 + hw2;
        float sn = 0.0f, sr = 0.0f;
        #pragma unroll
        for (int ww = 0; ww < 8; ww++) {
            sn += RedAll[ww * 1024 + tid];          // stride-1, conflict-free
            sr += RedAll[ww * 1024 + 512 + tid];
        }
        float hd = h[n2 * EMB + lane];
        float o_r = fmaxf(sr + rgcnBias_l[lane], 0.0f);
        float o_n = fmaxf(sn + nnBias_l[lane], 0.0f);
        hout[n2 * EMB + lane] = hd + o_r + o_n;
    }
}

// ---------------- launch ----------------

extern "C" void kernel_launch(void* const* d_in, const int* in_sizes, int n_in,
                              void* d_out, int out_size, void* d_ws, size_t ws_size,
                              hipStream_t stream) {
    const float* x        = (const float*)d_in[0];
    const int*   ei       = (const int*)d_in[1];
    const int*   et       = (const int*)d_in[2];
    const float* ed       = (const float*)d_in[3];
    const float* fcW      = (const float*)d_in[4];
    const float* fcb      = (const float*)d_in[5];
    const float* rgcnW    = (const float*)d_in[6];
    const float* rgcnRoot = (const float*)d_in[7];
    const float* rgcnBias = (const float*)d_in[8];
    const float* W1       = (const float*)d_in[9];
    const float* b1       = (const float*)d_in[10];
    const float* W2       = (const float*)d_in[11];
    const float* b2       = (const float*)d_in[12];
    const float* nnRoot   = (const float*)d_in[13];
    const float* nnBias   = (const float*)d_in[14];

    float* ws = (float*)d_ws;
    float* h_a    = ws;  ws += (size_t)N_NODES * EMB;
    float* h_b    = ws;  ws += (size_t)N_NODES * EMB;
    float* invdeg = ws;  ws += (size_t)N_NODES;
    float* invcnt = ws;  ws += (size_t)N_NODES * NREL;
    unsigned short* WB = (unsigned short*)ws;  ws += (size_t)83 * 1024 / 2;  // 83 rows bf16
    int2* edge2   = (int2*)ws;     ws += (size_t)N_EDGES * 2;
    int* row_ptr  = (int*)ws;      ws += (size_t)(N_NODES + 1);
    int* bsum     = (int*)ws;      ws += (size_t)NCHUNK;
    int* boff     = (int*)ws;      ws += (size_t)NCHUNK;
    int* deg      = (int*)ws;      ws += (size_t)N_NODES;       // deg..cursor contiguous (zeroed)
    int* relcnt   = (int*)ws;      ws += (size_t)N_NODES * NREL;
    int* cursor   = (int*)ws;      ws += (size_t)N_NODES;
    unsigned char* pairperm = (unsigned char*)ws;  ws += (size_t)(NBLK * NPB + 3) / 4;
    (void)in_sizes; (void)n_in; (void)out_size; (void)ws_size;

    zero_kernel<<<(10 * N_NODES + 255) / 256, 256, 0, stream>>>(deg, 10 * N_NODES);
    hist_kernel<<<(N_EDGES + 255) / 256, 256, 0, stream>>>(ei, et, deg, relcnt);
    bsum_kernel<<<NCHUNK, 256, 0, stream>>>(deg, bsum);
    inv_kernel<<<(N_NODES + 255) / 256, 256, 0, stream>>>(deg, relcnt, invdeg, invcnt);
    pairperm_kernel<<<(NBLK + 255) / 256, 256, 0, stream>>>(deg, pairperm);
    boff_kernel<<<1, 256, 0, stream>>>(bsum, boff, row_ptr);
    rptr_kernel<<<NCHUNK, 256, 0, stream>>>(deg, boff, row_ptr);
    scatter_kernel<<<(N_EDGES + 255) / 256, 256, 0, stream>>>(ei, et, ed, row_ptr,
                                                              cursor, edge2);
    wtbf_kernel<<<83, 256, 0, stream>>>(W2, b2, rgcnW, rgcnRoot, nnRoot, WB);
    fc_kernel<<<N_NODES / 8, 256, 0, stream>>>(x, fcW, fcb, h_a);

    const float* hin = h_a;
    float* houtb = h_b;
    for (int l = 0; l < NLAYER; l++) {
        float* dst = (l == NLAYER - 1) ? (float*)d_out : houtb;
        layer_kernel<<<N_NODES / NPB, 512, 0, stream>>>(
            hin, edge2, row_ptr, invdeg, invcnt, pairperm, W1, b1,
            WB, WB + (size_t)(33 + l * 10) * 1024,
            rgcnBias + (size_t)l * EMB,
            nnBias + (size_t)l * EMB,
            dst);
        float* old_in = (float*)hin;
        hin = dst;
        houtb = old_in;
    }
}

// Round 4
// 395.812 us; speedup vs baseline: 1.1697x; 1.0679x over previous
//
#include <hip/hip_runtime.h>

#define N_NODES 50000
#define N_EDGES 400000
#define EMB 32
#define NREL 8
#define NLAYER 5
#define NPB 16                 // nodes per block (8 waves x 2 balanced passes)
#define NBLK (N_NODES / NPB)   // 3125 node-blocks
#define KROWS 43               // 0..31 P, 32 Stot, 33..40 S_r, 41 h_dst(rgcn), 42 h_dst(nn)
#define NCHUNK 196             // ceil(50000/256) scan chunks
#define E2CAP (N_EDGES + 8 * N_NODES)   // 800000: padded edge capacity (pad <= +8/node)

typedef __attribute__((ext_vector_type(8))) short short8;   // 8 bf16 (4 VGPRs)
typedef __attribute__((ext_vector_type(4))) float f32x4;    // MFMA accumulator
typedef __attribute__((ext_vector_type(4))) unsigned int u32x4v;

__device__ __forceinline__ unsigned short f2bf(float f) {   // RNE f32 -> bf16
    unsigned u = __float_as_uint(f);
    unsigned r = u + 0x7FFF + ((u >> 16) & 1);
    return (unsigned short)(r >> 16);
}

// packed RNE f32x2 -> bf16x2 (lo = a, hi = b)
__device__ __forceinline__ unsigned cvt_pk(float a, float b) {
    unsigned r;
    asm("v_cvt_pk_bf16_f32 %0, %1, %2" : "=v"(r) : "v"(a), "v"(b));
    return r;
}

// ---------------- setup kernels ----------------

// zero counter block (deg..cursor, 10N ints) + sentinel-fill padded edge2 +
// zero the h pad row (row N_NODES) of both h buffers.
__global__ __launch_bounds__(256) void fill_kernel(int* __restrict__ zeroblk,
                                                   int2* __restrict__ edge2,
                                                   float* __restrict__ ha,
                                                   float* __restrict__ hb) {
    int i = blockIdx.x * 256 + threadIdx.x;
    if (i < E2CAP) edge2[i] = make_int2(N_NODES, 0);   // sentinel: src=pad row, rel=0, dist=0
    if (i < 10 * N_NODES) zeroblk[i] = 0;
    if (i < EMB) { ha[(size_t)N_NODES * EMB + i] = 0.0f; hb[(size_t)N_NODES * EMB + i] = 0.0f; }
}

__global__ __launch_bounds__(256) void hist_kernel(const int* __restrict__ ei,
                                                   const int* __restrict__ et,
                                                   int* __restrict__ deg,
                                                   int* __restrict__ relcnt) {
    int e = blockIdx.x * 256 + threadIdx.x;
    if (e < N_EDGES) {
        int d = ei[N_EDGES + e];           // dst = edge_index[1]
        atomicAdd(&deg[d], 1);
        atomicAdd(&relcnt[d * NREL + et[e]], 1);
    }
}

__device__ __forceinline__ int pdeg_of(int d) {   // ceil(max(d,1)/8)*8
    return (d > 0 ? d + 7 : 8) & ~7;
}

// fused: per-chunk padded-degree sums (bsum) + inv tables + per-block pairperm
__global__ __launch_bounds__(256) void nodeprep_kernel(const int* __restrict__ deg,
                                                       const int* __restrict__ relcnt,
                                                       int* __restrict__ bsum,
                                                       float* __restrict__ invdeg,
                                                       float* __restrict__ invcnt,
                                                       unsigned char* __restrict__ perm) {
    __shared__ int wsum[4];
    int tid = threadIdx.x, lane = tid & 63, wv = tid >> 6;
    int i = blockIdx.x * 256 + tid;
    int d = (i < N_NODES) ? deg[i] : 0;
    int v = (i < N_NODES) ? pdeg_of(d) : 0;
    #pragma unroll
    for (int off = 32; off > 0; off >>= 1) v += __shfl_down(v, off, 64);
    if (lane == 0) wsum[wv] = v;
    __syncthreads();
    if (tid == 0) bsum[blockIdx.x] = wsum[0] + wsum[1] + wsum[2] + wsum[3];
    if (i < N_NODES) {
        invdeg[i] = 1.0f / (float)(d > 0 ? d : 1);
        #pragma unroll
        for (int r = 0; r < NREL; r++) {
            int c = relcnt[i * NREL + r];
            invcnt[i * NREL + r] = 1.0f / (float)(c > 0 ? c : 1);
        }
    }
    if (i < NBLK) {   // degree-balanced pairing: sort 16 slots desc; wave w gets rank w & 15-w
        int dd[NPB]; unsigned char idx[NPB];
        #pragma unroll
        for (int k = 0; k < NPB; k++) { dd[k] = deg[i * NPB + k]; idx[k] = (unsigned char)k; }
        for (int a = 1; a < NPB; a++) {
            int dv = dd[a]; unsigned char iv = idx[a];
            int j = a - 1;
            while (j >= 0 && dd[j] < dv) { dd[j + 1] = dd[j]; idx[j + 1] = idx[j]; j--; }
            dd[j + 1] = dv; idx[j + 1] = iv;
        }
        #pragma unroll
        for (int k = 0; k < NPB; k++) perm[i * NPB + k] = idx[k];
    }
}

// scan chunk sums -> boff; row_ptr[N] = total padded edges
__global__ __launch_bounds__(256) void boff_kernel(const int* __restrict__ bsum,
                                                   int* __restrict__ boff,
                                                   int* __restrict__ row_ptr) {
    __shared__ int ws[4];
    int tid = threadIdx.x, lane = tid & 63, w = tid >> 6;
    int v = (tid < NCHUNK) ? bsum[tid] : 0;
    int incl = v;
    #pragma unroll
    for (int off = 1; off < 64; off <<= 1) {
        int t = __shfl_up(incl, off, 64);
        if (lane >= off) incl += t;
    }
    if (lane == 63) ws[w] = incl;
    __syncthreads();
    int add = 0;
    for (int j = 0; j < w; j++) add += ws[j];
    if (tid < NCHUNK) boff[tid] = add + incl - v;
    if (tid == 0) row_ptr[N_NODES] = ws[0] + ws[1] + ws[2] + ws[3];
}

// per-chunk exclusive scan (padded degrees) + chunk offset -> row_ptr
__global__ __launch_bounds__(256) void rptr_kernel(const int* __restrict__ deg,
                                                   const int* __restrict__ boff,
                                                   int* __restrict__ row_ptr) {
    __shared__ int ws[4];
    int tid = threadIdx.x, lane = tid & 63, w = tid >> 6;
    int i = blockIdx.x * 256 + tid;
    int v = (i < N_NODES) ? pdeg_of(deg[i]) : 0;
    int incl = v;
    #pragma unroll
    for (int off = 1; off < 64; off <<= 1) {
        int t = __shfl_up(incl, off, 64);
        if (lane >= off) incl += t;
    }
    if (lane == 63) ws[w] = incl;
    __syncthreads();
    int add = boff[blockIdx.x];
    for (int j = 0; j < w; j++) add += ws[j];
    if (i < N_NODES) row_ptr[i] = add + incl - v;
}

// scatter real edges into padded CSR slots + build per-wave table
// wavetab[b*8+w] = {slot0 | slot1<<8, pb0, pb1, pdeg0 | pdeg1<<16}
__global__ __launch_bounds__(256) void scatter_kernel(const int* __restrict__ ei,
                                                      const int* __restrict__ et,
                                                      const float* __restrict__ ed,
                                                      const int* __restrict__ row_ptr,
                                                      int* __restrict__ cursor,
                                                      int2* __restrict__ edge2,
                                                      const unsigned char* __restrict__ perm,
                                                      int4* __restrict__ wavetab) {
    int e = blockIdx.x * 256 + threadIdx.x;
    if (e < N_EDGES) {
        int d = ei[N_EDGES + e];
        int pos = row_ptr[d] + atomicAdd(&cursor[d], 1);
        edge2[pos] = make_int2(ei[e] | (et[e] << 16), __float_as_int(ed[e]));
    }
    if (e < NBLK * 8) {
        int b = e >> 3, wv = e & 7;
        int s0 = perm[b * NPB + wv], s1 = perm[b * NPB + (NPB - 1 - wv)];
        int nA = b * NPB + s0, nB = b * NPB + s1;
        int pb0 = row_ptr[nA], pd0 = row_ptr[nA + 1] - pb0;
        int pb1 = row_ptr[nB], pd1 = row_ptr[nB + 1] - pb1;
        wavetab[e] = make_int4(s0 | (s1 << 8), pb0, pb1, pd0 | (pd1 << 16));
    }
}

// transpose+bf16 contraction weights with interleaved-k permutation:
//   k-slot k holds input index i(k) = (k>>1) + ((k&1)<<4)
//   WB[m][o*32+k] = bf16(src_m[i(k)*32 + o])
__global__ __launch_bounds__(256) void wtbf_kernel(const float* __restrict__ W2,
                                                   const float* __restrict__ b2,
                                                   const float* __restrict__ rgcnW,
                                                   const float* __restrict__ rgcnRoot,
                                                   const float* __restrict__ nnRoot,
                                                   unsigned short* __restrict__ WB) {
    int m = blockIdx.x;
    const float* src;
    if (m < 32) src = W2 + (size_t)m * 1024;
    else if (m == 32) src = b2;
    else {
        int t = m - 33, l = t / 10, j = t % 10;
        src = (j < 8) ? rgcnW + (size_t)(l * 8 + j) * 1024
            : (j == 8) ? rgcnRoot + (size_t)l * 1024
                       : nnRoot + (size_t)l * 1024;
    }
    unsigned short* dst = WB + (size_t)m * 1024;
    #pragma unroll
    for (int c = 0; c < 4; c++) {
        int idx = c * 256 + threadIdx.x;
        int o = idx >> 5, k = idx & 31;
        int i = (k >> 1) + ((k & 1) << 4);
        dst[o * 32 + k] = f2bf(src[i * 32 + o]);
    }
}

// ---------------- fc: h0 = relu(x @ fc_W + fc_b), INTERLEAVED store ----------------
// storage index il(c) = 2*(c&15) + (c>>4): cols (m, m+16) adjacent -> float2 gathers.

__global__ __launch_bounds__(256) void fc_kernel(const float* __restrict__ x,
                                                 const float* __restrict__ W,
                                                 const float* __restrict__ b,
                                                 float* __restrict__ h) {
    __shared__ __align__(16) float xt[8][EMB];
    int tid = threadIdx.x;
    int nl = tid >> 5, lane = tid & 31;
    int n0 = blockIdx.x * 8;
    xt[tid >> 5][tid & 31] = x[n0 * EMB + tid];
    __syncthreads();
    float acc = b[lane];
    #pragma unroll
    for (int i = 0; i < EMB; i++) acc += xt[nl][i] * W[i * EMB + lane];
    int ol = ((lane & 15) << 1) | (lane >> 4);
    h[(n0 + nl) * EMB + ol] = fmaxf(acc, 0.0f);
}

// ---------------- fused layer kernel ----------------
// Padded CSR (pdeg multiple of 8, sentinel edges -> zero h row): NO per-lane masking.
// Edge k-slot map: k = quad*8 + 2jp + b <-> edge = c0 + jp*8 + quad*2 + b (wave-uniform
// jp guards). Edge pair load = one int4; gather = one float2 (interleaved h).
// Both passes' first-quad loads issue before the wrb2 barrier (overlapped chains).

__device__ __forceinline__ void gath(const float* __restrict__ h, int4 E, int m,
                                     float2& ga, float2& gb) {
    ga = *(const float2*)&h[((E.x & 0xFFFF) << 5) + 2 * m];
    gb = *(const float2*)&h[((E.z & 0xFFFF) << 5) + 2 * m];
}

__device__ __forceinline__ void proc_pair(int4 E, float2 ga, float2 gb,
                                          const float2* wrb2f, float w10_0, float w10_1,
                                          unsigned selm, int m,
                                          unsigned& A0s, unsigned& A1s, unsigned& ASs,
                                          unsigned& B0s, unsigned& B1s) {
    int ra = (E.x >> 16) & 7, rb = (E.z >> 16) & 7;
    float2 wa = wrb2f[ra * 16 + m];
    float2 wb = wrb2f[rb * 16 + m];
    float da = __int_as_float(E.y), db = __int_as_float(E.w);
    float hA0 = fmaxf(fmaf(da, w10_0, wa.x), 0.f);
    float hA1 = fmaxf(fmaf(da, w10_1, wa.y), 0.f);
    float hB0 = fmaxf(fmaf(db, w10_0, wb.x), 0.f);
    float hB1 = fmaxf(fmaf(db, w10_1, wb.y), 0.f);
    A0s = cvt_pk(hA0, hB0);
    A1s = cvt_pk(hA1, hB1);
    ASs = cvt_pk((float)((selm >> ra) & 1u), (float)((selm >> rb) & 1u));
    B0s = cvt_pk(ga.x, gb.x);
    B1s = cvt_pk(ga.y, gb.y);
}

__device__ __forceinline__ void mfma6(const unsigned* fa0v, const unsigned* fa1v,
                                      const unsigned* fasv, const unsigned* fb0v,
                                      const unsigned* fb1v,
                                      f32x4& aP00, f32x4& aP01, f32x4& aP10, f32x4& aP11,
                                      f32x4& aS0, f32x4& aS1) {
    u32x4v u0 = {fa0v[0], fa0v[1], fa0v[2], fa0v[3]};
    u32x4v u1 = {fa1v[0], fa1v[1], fa1v[2], fa1v[3]};
    u32x4v us = {fasv[0], fasv[1], fasv[2], fasv[3]};
    u32x4v v0 = {fb0v[0], fb0v[1], fb0v[2], fb0v[3]};
    u32x4v v1 = {fb1v[0], fb1v[1], fb1v[2], fb1v[3]};
    short8 A0 = __builtin_bit_cast(short8, u0);
    short8 A1 = __builtin_bit_cast(short8, u1);
    short8 AS = __builtin_bit_cast(short8, us);
    short8 B0 = __builtin_bit_cast(short8, v0);
    short8 B1 = __builtin_bit_cast(short8, v1);
    aP00 = __builtin_amdgcn_mfma_f32_16x16x32_bf16(A0, B0, aP00, 0, 0, 0);
    aP01 = __builtin_amdgcn_mfma_f32_16x16x32_bf16(A0, B1, aP01, 0, 0, 0);
    aP10 = __builtin_amdgcn_mfma_f32_16x16x32_bf16(A1, B0, aP10, 0, 0, 0);
    aP11 = __builtin_amdgcn_mfma_f32_16x16x32_bf16(A1, B1, aP11, 0, 0, 0);
    aS0  = __builtin_amdgcn_mfma_f32_16x16x32_bf16(AS, B0, aS0, 0, 0, 0);
    aS1  = __builtin_amdgcn_mfma_f32_16x16x32_bf16(AS, B1, aS1, 0, 0, 0);
}

__device__ __forceinline__ void edge_pass(const float* __restrict__ h,
                                          const int2* __restrict__ edge2,
                                          const float2* wrb2f,
                                          int pb, int pe, int quad, int m,
                                          float w10_0, float w10_1, unsigned selm,
                                          int4 E0, float2 g0a, float2 g0b,
                                          f32x4& aP00, f32x4& aP01, f32x4& aP10,
                                          f32x4& aP11, f32x4& aS0, f32x4& aS1) {
    {   // first chunk: jp0 from prefetch, jp1..3 dependent (wave-uniform guards)
        unsigned fa0v[4] = {0,0,0,0}, fa1v[4] = {0,0,0,0}, fasv[4] = {0,0,0,0};
        unsigned fb0v[4] = {0,0,0,0}, fb1v[4] = {0,0,0,0};
        proc_pair(E0, g0a, g0b, wrb2f, w10_0, w10_1, selm, m,
                  fa0v[0], fa1v[0], fasv[0], fb0v[0], fb1v[0]);
        if (pb + 8 < pe) {
            int4 E = *(const int4*)&edge2[pb + 8 + quad * 2];
            float2 ga, gb; gath(h, E, m, ga, gb);
            proc_pair(E, ga, gb, wrb2f, w10_0, w10_1, selm, m,
                      fa0v[1], fa1v[1], fasv[1], fb0v[1], fb1v[1]);
        }
        if (pb + 16 < pe) {
            int4 E = *(const int4*)&edge2[pb + 16 + quad * 2];
            float2 ga, gb; gath(h, E, m, ga, gb);
            proc_pair(E, ga, gb, wrb2f, w10_0, w10_1, selm, m,
                      fa0v[2], fa1v[2], fasv[2], fb0v[2], fb1v[2]);
        }
        if (pb + 24 < pe) {
            int4 E = *(const int4*)&edge2[pb + 24 + quad * 2];
            float2 ga, gb; gath(h, E, m, ga, gb);
            proc_pair(E, ga, gb, wrb2f, w10_0, w10_1, selm, m,
                      fa0v[3], fa1v[3], fasv[3], fb0v[3], fb1v[3]);
        }
        mfma6(fa0v, fa1v, fasv, fb0v, fb1v, aP00, aP01, aP10, aP11, aS0, aS1);
    }
    for (int c0 = pb + 32; c0 < pe; c0 += 32) {   // rare (deg > 32)
        unsigned fa0v[4] = {0,0,0,0}, fa1v[4] = {0,0,0,0}, fasv[4] = {0,0,0,0};
        unsigned fb0v[4] = {0,0,0,0}, fb1v[4] = {0,0,0,0};
        {
            int4 E = *(const int4*)&edge2[c0 + quad * 2];
            float2 ga, gb; gath(h, E, m, ga, gb);
            proc_pair(E, ga, gb, wrb2f, w10_0, w10_1, selm, m,
                      fa0v[0], fa1v[0], fasv[0], fb0v[0], fb1v[0]);
        }
        if (c0 + 8 < pe) {
            int4 E = *(const int4*)&edge2[c0 + 8 + quad * 2];
            float2 ga, gb; gath(h, E, m, ga, gb);
            proc_pair(E, ga, gb, wrb2f, w10_0, w10_1, selm, m,
                      fa0v[1], fa1v[1], fasv[1], fb0v[1], fb1v[1]);
        }
        if (c0 + 16 < pe) {
            int4 E = *(const int4*)&edge2[c0 + 16 + quad * 2];
            float2 ga, gb; gath(h, E, m, ga, gb);
            proc_pair(E, ga, gb, wrb2f, w10_0, w10_1, selm, m,
                      fa0v[2], fa1v[2], fasv[2], fb0v[2], fb1v[2]);
        }
        if (c0 + 24 < pe) {
            int4 E = *(const int4*)&edge2[c0 + 24 + quad * 2];
            float2 ga, gb; gath(h, E, m, ga, gb);
            proc_pair(E, ga, gb, wrb2f, w10_0, w10_1, selm, m,
                      fa0v[3], fa1v[3], fasv[3], fb0v[3], fb1v[3]);
        }
        mfma6(fa0v, fa1v, fasv, fb0v, fb1v, aP00, aP01, aP10, aP11, aS0, aS1);
    }
}

__device__ __forceinline__ void stage_node(unsigned short (*P)[EMB], int quad, int m,
                                           float idg, const float* __restrict__ invcnt_n,
                                           const float* __restrict__ hrow,
                                           const f32x4& aP00, const f32x4& aP01,
                                           const f32x4& aP10, const f32x4& aP11,
                                           const f32x4& aS0, const f32x4& aS1) {
    #pragma unroll
    for (int reg = 0; reg < 4; ++reg) {
        const int row = quad * 4 + reg;       // D: row = quad*4+reg, col = m (tile0)/m+16 (tile1)
        *(unsigned*)&P[row][2 * m]      = cvt_pk(aP00[reg] * idg, aP01[reg] * idg);
        *(unsigned*)&P[row + 16][2 * m] = cvt_pk(aP10[reg] * idg, aP11[reg] * idg);
        if (row <= 8) {                        // S rows: 0 -> Stot(32), 1..8 -> S_r(33..40)
            const float sc = (row == 0) ? idg : invcnt_n[row - 1];
            *(unsigned*)&P[32 + row][2 * m] = cvt_pk(aS0[reg] * sc, aS1[reg] * sc);
        }
    }
    if (quad < 2) {                            // rows 41/42: h_dst (interleaved float2)
        float2 hh = *(const float2*)&hrow[2 * m];
        *(unsigned*)&P[41 + quad][2 * m] = cvt_pk(hh.x, hh.y);
    }
}

__global__ __launch_bounds__(512, 6) void layer_kernel(
    const float* __restrict__ h,
    const int2* __restrict__ edge2,
    const int4* __restrict__ wavetab,
    const float* __restrict__ invdeg,
    const float* __restrict__ invcnt,
    const float* __restrict__ W1,
    const float* __restrict__ b1,
    const unsigned short* __restrict__ WBs,   // rows 0..32 (W2^T, b2^T)
    const unsigned short* __restrict__ WBl,   // rows 33..42
    const float* __restrict__ rgcnBias_l,
    const float* __restrict__ nnBias_l,
    float* __restrict__ hout,
    int last)
{
    __shared__ __align__(16) unsigned short P_lds[NPB][KROWS][EMB];  // 44032 B
    __shared__ __align__(16) float2 wrb2f[NREL * 16];                // [r*16+m] = (W1[1+r][m]+b1[m], W1[1+r][m+16]+b1[m+16])
    // total 45056 B -> 3 blocks/CU

    const int tid = threadIdx.x;
    const int n0 = blockIdx.x * NPB;

    if (tid < 128) {
        int r = tid >> 4, mi = tid & 15;
        wrb2f[r * 16 + mi] = make_float2(W1[(1 + r) * EMB + mi] + b1[mi],
                                         W1[(1 + r) * EMB + mi + 16] + b1[mi + 16]);
    }

    const int l    = tid & 63;
    const int w    = tid >> 6;        // wave 0..7
    const int quad = l >> 4;          // 0..3
    const int m    = l & 15;
    const float w10_0 = W1[m];
    const float w10_1 = W1[m + 16];
    const unsigned selm = (m == 0) ? 0xFFu : (m <= 8 ? (1u << (m - 1)) : 0u);

    // one-load wave schedule + prefetch BOTH passes' first quad (overlap chains)
    int4 wt = wavetab[blockIdx.x * 8 + w];
    const int hw0 = wt.x & 0xFF, hw1 = (wt.x >> 8) & 0xFF;
    const int pb0 = wt.y, pe0 = wt.y + (wt.w & 0xFFFF);
    const int pb1 = wt.z, pe1 = wt.z + (int)((unsigned)wt.w >> 16);
    int4 E0 = *(const int4*)&edge2[pb0 + quad * 2];
    int4 E1 = *(const int4*)&edge2[pb1 + quad * 2];
    float2 g0a, g0b, g1a, g1b;
    gath(h, E0, m, g0a, g0b);
    gath(h, E1, m, g1a, g1b);

    __syncthreads();   // wrb2f ready

    {   // pass 0
        f32x4 aP00 = {0,0,0,0}, aP01 = {0,0,0,0}, aP10 = {0,0,0,0}, aP11 = {0,0,0,0};
        f32x4 aS0 = {0,0,0,0}, aS1 = {0,0,0,0};
        edge_pass(h, edge2, wrb2f, pb0, pe0, quad, m, w10_0, w10_1, selm,
                  E0, g0a, g0b, aP00, aP01, aP10, aP11, aS0, aS1);
        const int n = n0 + hw0;
        stage_node(P_lds[hw0], quad, m, invdeg[n], invcnt + (size_t)n * NREL,
                   h + (size_t)n * EMB, aP00, aP01, aP10, aP11, aS0, aS1);
    }
    {   // pass 1
        f32x4 aP00 = {0,0,0,0}, aP01 = {0,0,0,0}, aP10 = {0,0,0,0}, aP11 = {0,0,0,0};
        f32x4 aS0 = {0,0,0,0}, aS1 = {0,0,0,0};
        edge_pass(h, edge2, wrb2f, pb1, pe1, quad, m, w10_0, w10_1, selm,
                  E1, g1a, g1b, aP00, aP01, aP10, aP11, aS0, aS1);
        const int n = n0 + hw1;
        stage_node(P_lds[hw1], quad, m, invdeg[n], invcnt + (size_t)n * NREL,
                   h + (size_t)n * EMB, aP00, aP01, aP10, aP11, aS0, aS1);
    }
    __syncthreads();

    // ---------- MFMA contraction (WB k-order matches staged interleaved columns) ----------
    const int node16 = l & 15;
    const int o0 = l & 15;                    // B n-index (tile 0); tile 1 = +16

    f32x4 accN0 = {0,0,0,0}, accN1 = {0,0,0,0};
    f32x4 accR0 = {0,0,0,0}, accR1 = {0,0,0,0};

    #pragma unroll
    for (int j = 0; j < 6; j++) {
        const int rr = w + 8 * j;             // wave-uniform
        if (rr < KROWS) {
            const unsigned short* Bsrc = (rr < 33) ? (WBs + (size_t)rr * 1024)
                                                   : (WBl + (size_t)(rr - 33) * 1024);
            short8 bf0 = *(const short8*)(Bsrc + o0 * 32 + quad * 8);
            short8 bf1 = *(const short8*)(Bsrc + (o0 + 16) * 32 + quad * 8);
            short8 a = *(const short8*)&P_lds[node16][rr][quad * 8];
            if (rr <= 32 || rr == 42) {
                accN0 = __builtin_amdgcn_mfma_f32_16x16x32_bf16(a, bf0, accN0, 0, 0, 0);
                accN1 = __builtin_amdgcn_mfma_f32_16x16x32_bf16(a, bf1, accN1, 0, 0, 0);
            } else {
                accR0 = __builtin_amdgcn_mfma_f32_16x16x32_bf16(a, bf0, accR0, 0, 0, 0);
                accR1 = __builtin_amdgcn_mfma_f32_16x16x32_bf16(a, bf1, accR1, 0, 0, 0);
            }
        }
    }
    __syncthreads();                          // all A-reads done; safe to overlay RedAll

    // ---------- deterministic cross-wave reduction (no atomics) ----------
    float* RedAll = (float*)&P_lds[0][0][0];  // 8 waves x 1024 floats = 32 KiB < 44 KiB
    {
        float* my = RedAll + w * 1024;
        #pragma unroll
        for (int reg = 0; reg < 4; reg++) {
            int nd = quad * 4 + reg;          // C/D: row(m=node)=quad*4+reg, col(n=o)=lane&15
            my[nd * 32 + o0]            = accN0[reg];
            my[nd * 32 + o0 + 16]       = accN1[reg];
            my[512 + nd * 32 + o0]      = accR0[reg];
            my[512 + nd * 32 + o0 + 16] = accR1[reg];
        }
    }
    __syncthreads();

    // ---------- epilogue (node slot = tid>>5, logical output col = tid&31) ----------
    {
        const int hw2 = tid >> 5, lane = tid & 31;
        const int n2 = n0 + hw2;
        float sn = 0.0f, sr = 0.0f;
        #pragma unroll
        for (int ww = 0; ww < 8; ww++) {
            sn += RedAll[ww * 1024 + tid];          // stride-1, conflict-free
            sr += RedAll[ww * 1024 + 512 + tid];
        }
        const int il = ((lane & 15) << 1) | (lane >> 4);
        float hd = h[(size_t)n2 * EMB + il];
        float o_r = fmaxf(sr + rgcnBias_l[lane], 0.0f);
        float o_n = fmaxf(sn + nnBias_l[lane], 0.0f);
        hout[(size_t)n2 * EMB + (last ? lane : il)] = hd + o_r + o_n;
    }
}

// ---------------- launch ----------------

extern "C" void kernel_launch(void* const* d_in, const int* in_sizes, int n_in,
                              void* d_out, int out_size, void* d_ws, size_t ws_size,
                              hipStream_t stream) {
    const float* x        = (const float*)d_in[0];
    const int*   ei       = (const int*)d_in[1];
    const int*   et       = (const int*)d_in[2];
    const float* ed       = (const float*)d_in[3];
    const float* fcW      = (const float*)d_in[4];
    const float* fcb      = (const float*)d_in[5];
    const float* rgcnW    = (const float*)d_in[6];
    const float* rgcnRoot = (const float*)d_in[7];
    const float* rgcnBias = (const float*)d_in[8];
    const float* W1       = (const float*)d_in[9];
    const float* b1       = (const float*)d_in[10];
    const float* W2       = (const float*)d_in[11];
    const float* b2       = (const float*)d_in[12];
    const float* nnRoot   = (const float*)d_in[13];
    const float* nnBias   = (const float*)d_in[14];

    float* ws = (float*)d_ws;
    float* h_a    = ws;  ws += (size_t)(N_NODES + 1) * EMB;   // +1 zero pad row
    float* h_b    = ws;  ws += (size_t)(N_NODES + 1) * EMB;
    float* invdeg = ws;  ws += (size_t)N_NODES;
    float* invcnt = ws;  ws += (size_t)N_NODES * NREL;
    unsigned short* WB = (unsigned short*)ws;  ws += (size_t)83 * 1024 / 2;
    int2* edge2   = (int2*)ws;     ws += (size_t)E2CAP * 2;
    int* row_ptr  = (int*)ws;      ws += (size_t)(N_NODES + 1);
    int* bsum     = (int*)ws;      ws += (size_t)NCHUNK;
    int* boff     = (int*)ws;      ws += (size_t)NCHUNK;
    int* deg      = (int*)ws;      ws += (size_t)N_NODES;     // deg..cursor contiguous (zeroed)
    int* relcnt   = (int*)ws;      ws += (size_t)N_NODES * NREL;
    int* cursor   = (int*)ws;      ws += (size_t)N_NODES;
    unsigned char* perm = (unsigned char*)ws;  ws += (size_t)NBLK * NPB / 4;
    int4* wavetab = (int4*)ws;     ws += (size_t)NBLK * 8 * 4;
    (void)in_sizes; (void)n_in; (void)out_size; (void)ws_size;

    fill_kernel<<<(E2CAP + 255) / 256, 256, 0, stream>>>(deg, edge2, h_a, h_b);
    hist_kernel<<<(N_EDGES + 255) / 256, 256, 0, stream>>>(ei, et, deg, relcnt);
    nodeprep_kernel<<<NCHUNK, 256, 0, stream>>>(deg, relcnt, bsum, invdeg, invcnt, perm);
    boff_kernel<<<1, 256, 0, stream>>>(bsum, boff, row_ptr);
    rptr_kernel<<<NCHUNK, 256, 0, stream>>>(deg, boff, row_ptr);
    scatter_kernel<<<(N_EDGES + 255) / 256, 256, 0, stream>>>(ei, et, ed, row_ptr,
                                                              cursor, edge2, perm, wavetab);
    wtbf_kernel<<<83, 256, 0, stream>>>(W2, b2, rgcnW, rgcnRoot, nnRoot, WB);
    fc_kernel<<<N_NODES / 8, 256, 0, stream>>>(x, fcW, fcb, h_a);

    const float* hin = h_a;
    float* houtb = h_b;
    for (int l = 0; l < NLAYER; l++) {
        float* dst = (l == NLAYER - 1) ? (float*)d_out : houtb;
        layer_kernel<<<NBLK, 512, 0, stream>>>(
            hin, edge2, wavetab, invdeg, invcnt, W1, b1,
            WB, WB + (size_t)(33 + l * 10) * 1024,
            rgcnBias + (size_t)l * EMB,
            nnBias + (size_t)l * EMB,
            dst, (l == NLAYER - 1) ? 1 : 0);
        float* old_in = (float*)hin;
        hin = dst;
        houtb = old_in;
    }
}